// Round 1
// baseline (6352.593 us; speedup 1.0000x reference)
//
#include <hip/hip_runtime.h>
#include <hip/hip_bf16.h>
#include <math.h>

#define BB   4
#define NN   100000
#define NFEAT 11
#define NSP  512
#define NSEG (BB*NSP)     // 2048
#define NPTS (BB*NN)      // 400000
#define H2   256
#define H3   512
#define EE   384
#define PADY 20           // y1sT row pad (floats) -> 80B rows, float4-aligned

__global__ void zero_counts(int* __restrict__ counts, int* __restrict__ cursor) {
  int i = blockIdx.x * blockDim.x + threadIdx.x;
  if (i < NSEG) { counts[i] = 0; cursor[i] = 0; }
}

__global__ void prep_weights(const float* __restrict__ W1, const float* __restrict__ b1,
                             const float* __restrict__ W2, const float* __restrict__ b2,
                             const float* __restrict__ W3, const float* __restrict__ W4,
                             float* __restrict__ W12, float* __restrict__ b12,
                             float* __restrict__ W3T, float* __restrict__ W4T) {
  int u = blockIdx.x * blockDim.x + threadIdx.x;
  if (u < H2 * NFEAT) {
    int c = u / NFEAT, f = u - c * NFEAT;
    float acc = 0.f;
    for (int j = 0; j < 128; ++j) acc += W2[c * 128 + j] * W1[j * NFEAT + f];
    W12[u] = acc;
  } else if (u < H2 * NFEAT + H2) {
    int c = u - H2 * NFEAT;
    float acc = b2[c];
    for (int j = 0; j < 128; ++j) acc += W2[c * 128 + j] * b1[j];
    b12[c] = acc;
  } else if (u < H2 * NFEAT + H2 + H3 * H3) {
    int v = u - (H2 * NFEAT + H2);
    int k = v >> 9, o = v & (H3 - 1);
    W3T[v] = W3[o * H3 + k];                // W3T[k][o] = W3[o][k]
  } else if (u < H2 * NFEAT + H2 + H3 * H3 + H3 * EE) {
    int v = u - (H2 * NFEAT + H2 + H3 * H3);
    int c = v / EE, o = v - c * EE;
    W4T[v] = W4[o * H3 + c];                // W4T[c][o] = W4[o][c]
  }
}

__global__ void hist_kernel(const int* __restrict__ sidx, int* __restrict__ counts) {
  int i = blockIdx.x * blockDim.x + threadIdx.x;
  if (i < NPTS) {
    int seg = sidx[i] + (i / NN) * NSP;
    atomicAdd(&counts[seg], 1);
  }
}

__global__ void scan_kernel(const int* __restrict__ counts, int* __restrict__ offs) {
  __shared__ int buf[1024];
  int t = threadIdx.x;
  int c0 = counts[2 * t], c1 = counts[2 * t + 1];
  int s = c0 + c1;
  buf[t] = s;
  __syncthreads();
  for (int d = 1; d < 1024; d <<= 1) {
    int add = (t >= d) ? buf[t - d] : 0;
    __syncthreads();
    buf[t] += add;
    __syncthreads();
  }
  int incl = buf[t];
  int excl = incl - s;
  offs[2 * t] = excl;
  offs[2 * t + 1] = excl + c0;
  if (t == 1023) offs[2048] = incl;
}

__global__ void scatter_kernel(const int* __restrict__ sidx, const int* __restrict__ offs,
                               int* __restrict__ cursor, int* __restrict__ perm) {
  int i = blockIdx.x * blockDim.x + threadIdx.x;
  if (i < NPTS) {
    int seg = sidx[i] + (i / NN) * NSP;
    int pos = offs[seg] + atomicAdd(&cursor[seg], 1);
    perm[pos] = i;
  }
}

__global__ __launch_bounds__(256) void fused_kernel(
    const float* __restrict__ x, const int* __restrict__ perm,
    const int* __restrict__ offs,
    const float* __restrict__ W12, const float* __restrict__ b12,
    const float* __restrict__ W3T, const float* __restrict__ b3,
    const float* __restrict__ W4T, const float* __restrict__ b4,
    float* __restrict__ out) {
  __shared__ float W12s[H2 * NFEAT];   // 11.0 KB
  __shared__ float b12s[H2];           // 1 KB
  __shared__ float xs[64 * NFEAT];     // 2.75 KB
  __shared__ float gs[H2];             // 1 KB
  __shared__ float gpart[H3];          // 2 KB
  __shared__ float hsT[H2 * 16];       // 16 KB   hsT[c][p]
  __shared__ float y1sT[H3 * PADY];    // 40 KB   y1sT[o][p], padded rows

  const int s = blockIdx.x;
  const int t = threadIdx.x;
  const int beg = offs[s];
  const int cnt = offs[s + 1] - beg;

  if (cnt == 0) {
    for (int u = t; u < EE; u += 256) out[s * EE + u] = -INFINITY;
    return;
  }

  for (int u = t; u < H2 * NFEAT; u += 256) W12s[u] = W12[u];
  b12s[t] = b12[t];
  __syncthreads();

  // ---- pass 1: per-channel segment max of h (thread t owns channel t) ----
  float gm = -INFINITY;
  for (int base = 0; base < cnt; base += 64) {
    int m = min(64, cnt - base);
    __syncthreads();
    for (int u = t; u < m * NFEAT; u += 256) {
      int p = u / NFEAT, f = u - p * NFEAT;
      xs[u] = x[(size_t)perm[beg + base + p] * NFEAT + f];
    }
    __syncthreads();
    for (int p = 0; p < m; ++p) {
      float acc = b12s[t];
      #pragma unroll
      for (int f = 0; f < NFEAT; ++f) acc += W12s[t * NFEAT + f] * xs[p * NFEAT + f];
      gm = fmaxf(gm, acc);
    }
  }
  gs[t] = gm;
  __syncthreads();

  // ---- gpart[o] = b3[o] + sum_c W3[o][c] * g[c]  (once per segment) ----
  {
    float a0 = b3[t], a1 = b3[t + 256];
    for (int c = 0; c < H2; ++c) {
      float gv = gs[c];
      a0 += W3T[c * H3 + t] * gv;
      a1 += W3T[c * H3 + t + 256] * gv;
    }
    gpart[t] = a0;
    gpart[t + 256] = a1;
  }
  __syncthreads();

  const bool o1valid = (t < 128);
  const float bb0 = b4[t];
  const float bb1 = o1valid ? b4[256 + t] : 0.f;
  float om0 = -INFINITY, om1 = -INFINITY;

  // ---- pass 2: 16-point tiles through layer3h + layer4 ----
  for (int base = 0; base < cnt; base += 16) {
    int m = min(16, cnt - base);
    __syncthreads();
    for (int u = t; u < 16 * NFEAT; u += 256) {
      int p = u / NFEAT, f = u - p * NFEAT;
      xs[u] = (p < m) ? x[(size_t)perm[beg + base + p] * NFEAT + f] : 0.f;
    }
    __syncthreads();

    // recompute h, store transposed hsT[c][p]
    #pragma unroll
    for (int i = 0; i < 16; ++i) {
      int c = i * 16 + (t >> 4), p = t & 15;
      float acc = b12s[c];
      #pragma unroll
      for (int f = 0; f < NFEAT; ++f) acc += W12s[c * NFEAT + f] * xs[p * NFEAT + f];
      hsT[i * 256 + t] = acc;   // == hsT[c*16 + p]
    }
    __syncthreads();

    // layer3h: thread t -> outputs o=t and o=t+256, 16 points in registers
    {
      float a0[16], a1[16];
      const float g0 = gpart[t], g1 = gpart[t + 256];
      #pragma unroll
      for (int p = 0; p < 16; ++p) { a0[p] = g0; a1[p] = g1; }
      for (int c = 0; c < H2; ++c) {
        float w0 = W3T[(H2 + c) * H3 + t];
        float w1 = W3T[(H2 + c) * H3 + t + 256];
        const float4* h4 = reinterpret_cast<const float4*>(&hsT[c * 16]);
        float hv[16];
        *reinterpret_cast<float4*>(&hv[0])  = h4[0];
        *reinterpret_cast<float4*>(&hv[4])  = h4[1];
        *reinterpret_cast<float4*>(&hv[8])  = h4[2];
        *reinterpret_cast<float4*>(&hv[12]) = h4[3];
        #pragma unroll
        for (int p = 0; p < 16; ++p) { a0[p] += w0 * hv[p]; a1[p] += w1 * hv[p]; }
      }
      #pragma unroll
      for (int p = 0; p < 16; ++p) {
        y1sT[t * PADY + p]         = fmaxf(a0[p], 0.f);
        y1sT[(t + 256) * PADY + p] = fmaxf(a1[p], 0.f);
      }
    }
    __syncthreads();

    // layer4: thread t -> output t; threads <128 also output 256+t
    {
      float acc0[16], acc1[16];
      #pragma unroll
      for (int p = 0; p < 16; ++p) { acc0[p] = bb0; acc1[p] = bb1; }
      for (int c = 0; c < H3; ++c) {
        float w0 = W4T[c * EE + t];
        const float4* y4 = reinterpret_cast<const float4*>(&y1sT[c * PADY]);
        float yv[16];
        *reinterpret_cast<float4*>(&yv[0])  = y4[0];
        *reinterpret_cast<float4*>(&yv[4])  = y4[1];
        *reinterpret_cast<float4*>(&yv[8])  = y4[2];
        *reinterpret_cast<float4*>(&yv[12]) = y4[3];
        #pragma unroll
        for (int p = 0; p < 16; ++p) acc0[p] += w0 * yv[p];
        if (o1valid) {
          float w1 = W4T[c * EE + 256 + t];
          #pragma unroll
          for (int p = 0; p < 16; ++p) acc1[p] += w1 * yv[p];
        }
      }
      #pragma unroll
      for (int p = 0; p < 16; ++p) {
        if (p < m) {
          om0 = fmaxf(om0, acc0[p]);
          if (o1valid) om1 = fmaxf(om1, acc1[p]);
        }
      }
    }
  }

  out[s * EE + t] = om0;
  if (o1valid) out[s * EE + 256 + t] = om1;
}

extern "C" void kernel_launch(void* const* d_in, const int* in_sizes, int n_in,
                              void* d_out, int out_size, void* d_ws, size_t ws_size,
                              hipStream_t stream) {
  (void)in_sizes; (void)n_in; (void)out_size; (void)ws_size;
  const float* x    = (const float*)d_in[0];
  const int*   sidx = (const int*)d_in[1];
  const float* W1   = (const float*)d_in[2];
  const float* b1   = (const float*)d_in[3];
  const float* W2   = (const float*)d_in[4];
  const float* b2   = (const float*)d_in[5];
  const float* W3   = (const float*)d_in[6];
  const float* b3   = (const float*)d_in[7];
  const float* W4   = (const float*)d_in[8];
  const float* b4   = (const float*)d_in[9];
  float* out = (float*)d_out;

  char* ws = (char*)d_ws;
  size_t off = 0;
  auto alloc = [&](size_t bytes) {
    void* p = ws + off;
    off = (off + bytes + 255) & ~(size_t)255;
    return p;
  };
  int* counts  = (int*)alloc(NSEG * 4);
  int* cursor  = (int*)alloc(NSEG * 4);
  int* offs    = (int*)alloc((NSEG + 1) * 4);
  int* perm    = (int*)alloc((size_t)NPTS * 4);
  float* W12   = (float*)alloc(H2 * NFEAT * 4);
  float* b12   = (float*)alloc(H2 * 4);
  float* W3T   = (float*)alloc((size_t)H3 * H3 * 4);
  float* W4T   = (float*)alloc((size_t)H3 * EE * 4);

  zero_counts<<<(NSEG + 255) / 256, 256, 0, stream>>>(counts, cursor);
  const int preptotal = H2 * NFEAT + H2 + H3 * H3 + H3 * EE;
  prep_weights<<<(preptotal + 255) / 256, 256, 0, stream>>>(W1, b1, W2, b2, W3, W4,
                                                            W12, b12, W3T, W4T);
  hist_kernel<<<(NPTS + 255) / 256, 256, 0, stream>>>(sidx, counts);
  scan_kernel<<<1, 1024, 0, stream>>>(counts, offs);
  scatter_kernel<<<(NPTS + 255) / 256, 256, 0, stream>>>(sidx, offs, cursor, perm);
  fused_kernel<<<NSEG, 256, 0, stream>>>(x, perm, offs, W12, b12, W3T, b3, W4T, b4, out);
}

// Round 2
// 2203.212 us; speedup vs baseline: 2.8833x; 2.8833x over previous
//
#include <hip/hip_runtime.h>
#include <hip/hip_bf16.h>
#include <math.h>

#define BB    4
#define NN    100000
#define NFEAT 11
#define NSP   512
#define NSEG  (BB*NSP)     // 2048
#define NPTS  (BB*NN)      // 400000
#define H2    256
#define H3    512
#define EE    384

typedef __attribute__((ext_vector_type(8))) short short8;
typedef __attribute__((ext_vector_type(4))) float f32x4;

__device__ __forceinline__ ushort f2bf(float f) {
  unsigned u = __builtin_bit_cast(unsigned, f);
  unsigned r = (u + 0x7FFFu + ((u >> 16) & 1u)) >> 16;
  return (ushort)r;
}

// ---------------- sort pipeline (unchanged from R1, validated) ----------------
__global__ void zero_counts(int* __restrict__ counts, int* __restrict__ cursor) {
  int i = blockIdx.x * blockDim.x + threadIdx.x;
  if (i < NSEG) { counts[i] = 0; cursor[i] = 0; }
}

__global__ void hist_kernel(const int* __restrict__ sidx, int* __restrict__ counts) {
  int i = blockIdx.x * blockDim.x + threadIdx.x;
  if (i < NPTS) {
    int seg = sidx[i] + (i / NN) * NSP;
    atomicAdd(&counts[seg], 1);
  }
}

__global__ void scan_kernel(const int* __restrict__ counts, int* __restrict__ offs) {
  __shared__ int buf[1024];
  int t = threadIdx.x;
  int c0 = counts[2 * t], c1 = counts[2 * t + 1];
  int s = c0 + c1;
  buf[t] = s;
  __syncthreads();
  for (int d = 1; d < 1024; d <<= 1) {
    int add = (t >= d) ? buf[t - d] : 0;
    __syncthreads();
    buf[t] += add;
    __syncthreads();
  }
  int incl = buf[t];
  int excl = incl - s;
  offs[2 * t] = excl;
  offs[2 * t + 1] = excl + c0;
  if (t == 1023) offs[2048] = incl;
}

__global__ void scatter_kernel(const int* __restrict__ sidx, const int* __restrict__ offs,
                               int* __restrict__ cursor, int* __restrict__ perm) {
  int i = blockIdx.x * blockDim.x + threadIdx.x;
  if (i < NPTS) {
    int seg = sidx[i] + (i / NN) * NSP;
    int pos = offs[seg] + atomicAdd(&cursor[seg], 1);
    perm[pos] = i;
  }
}

// ---------------- weight prep: fold W12, transpose W3g, frag-pack W3h/W4 ------
// W3hP fragment packing (bf16): idx = ((ks*32 + nt)*64 + l)*8 + j
//   holds B[k][n] = W3[n][256+k], n = nt*16 + (l&15), k = ks*32 + (l>>4)*8 + j
// W4P: idx = ((ks*24 + nt)*64 + l)*8 + j, B[k][n] = W4[n][k], 16 ksteps, 24 ntiles
__global__ void prep_weights(const float* __restrict__ W1, const float* __restrict__ b1,
                             const float* __restrict__ W2, const float* __restrict__ b2,
                             const float* __restrict__ W3, const float* __restrict__ W4,
                             float* __restrict__ W12, float* __restrict__ b12,
                             float* __restrict__ W3gT, ushort* __restrict__ W3hP,
                             ushort* __restrict__ W4P) {
  int u = blockIdx.x * blockDim.x + threadIdx.x;
  if (u < H2 * NFEAT) {                           // 2816
    int c = u / NFEAT, f = u - c * NFEAT;
    float acc = 0.f;
    for (int j = 0; j < 128; ++j) acc += W2[c * 128 + j] * W1[j * NFEAT + f];
    W12[u] = acc;
  } else if (u < 3072) {                          // b12: 256
    int c = u - H2 * NFEAT;
    float acc = b2[c];
    for (int j = 0; j < 128; ++j) acc += W2[c * 128 + j] * b1[j];
    b12[c] = acc;
  } else if (u < 3072 + 131072) {                 // W3gT fp32 [c][o], c<256
    int v = u - 3072;
    int c = v >> 9, o = v & 511;
    W3gT[v] = W3[o * H3 + c];
  } else if (u < 134144 + 16384) {                // W3hP: 8ks*32nt*64l
    int v = u - 134144;
    int ks = v >> 11, rem = v & 2047;
    int nt = rem >> 6, l = rem & 63;
    int n = nt * 16 + (l & 15);
    #pragma unroll
    for (int j = 0; j < 8; ++j) {
      int k = ks * 32 + (l >> 4) * 8 + j;
      W3hP[(size_t)v * 8 + j] = f2bf(W3[n * H3 + H2 + k]);
    }
  } else if (u < 150528 + 24576) {                // W4P: 16ks*24nt*64l
    int v = u - 150528;
    int ks = v / 1536, rem = v - ks * 1536;
    int nt = rem >> 6, l = rem & 63;
    int n = nt * 16 + (l & 15);
    #pragma unroll
    for (int j = 0; j < 8; ++j) {
      int k = ks * 32 + (l >> 4) * 8 + j;
      W4P[(size_t)v * 8 + j] = f2bf(W4[n * H3 + k]);
    }
  }
}

// ---------------- per-segment: g = segmax(h) (fp32), gpart = b3 + W3g @ g -----
__global__ __launch_bounds__(256) void seg_kernel(
    const float* __restrict__ x, const int* __restrict__ perm,
    const int* __restrict__ offs,
    const float* __restrict__ W12, const float* __restrict__ b12,
    const float* __restrict__ W3gT, const float* __restrict__ b3,
    float* __restrict__ gpartG) {
  __shared__ float W12s[H2 * NFEAT];
  __shared__ float b12s[H2];
  __shared__ float xs[64 * NFEAT];
  __shared__ float gs[H2];

  const int s = blockIdx.x;
  const int t = threadIdx.x;
  const int beg = offs[s];
  const int cnt = offs[s + 1] - beg;
  if (cnt == 0) return;   // main_kernel writes -inf directly; gpart unused

  for (int u = t; u < H2 * NFEAT; u += 256) W12s[u] = W12[u];
  b12s[t] = b12[t];
  __syncthreads();

  float gm = -INFINITY;
  for (int base = 0; base < cnt; base += 64) {
    int m = min(64, cnt - base);
    __syncthreads();
    for (int u = t; u < m * NFEAT; u += 256) {
      int p = u / NFEAT, f = u - p * NFEAT;
      xs[u] = x[(size_t)perm[beg + base + p] * NFEAT + f];
    }
    __syncthreads();
    for (int p = 0; p < m; ++p) {
      float acc = b12s[t];
      #pragma unroll
      for (int f = 0; f < NFEAT; ++f) acc += W12s[t * NFEAT + f] * xs[p * NFEAT + f];
      gm = fmaxf(gm, acc);
    }
  }
  gs[t] = gm;
  __syncthreads();

  float a0 = b3[t], a1 = b3[t + 256];
  for (int c = 0; c < H2; ++c) {
    float gv = gs[c];
    a0 += W3gT[c * H3 + t] * gv;
    a1 += W3gT[c * H3 + t + 256] * gv;
  }
  gpartG[(size_t)s * H3 + t] = a0;
  gpartG[(size_t)s * H3 + t + 256] = a1;
}

// ---------------- main fused MFMA kernel: one block per segment ----------------
// 4 waves. Per 64-point M-tile: recompute h (fp32 VALU) -> bf16 swizzled LDS,
// layer3 (K=256, N=512 in 2 halves x 2 quarters) MFMA + gpart bias + relu ->
// bf16 swizzled LDS, layer4 (K=512 over halves, N=384) MFMA, masked seg-max.
__global__ __launch_bounds__(256, 2) void main_kernel(
    const float* __restrict__ x, const int* __restrict__ perm,
    const int* __restrict__ offs,
    const float* __restrict__ W12, const float* __restrict__ b12,
    const ushort* __restrict__ W3hP, const ushort* __restrict__ W4P,
    const float* __restrict__ gpartG, const float* __restrict__ b4,
    float* __restrict__ out) {
  __shared__ __align__(16) ushort hsE[64 * 256];   // 32 KB, h tile bf16, swizzled
  __shared__ __align__(16) ushort dynE[64 * 256];  // 32 KB: (xs|W12s|b12s) overlay, then y1 tile

  const int s = blockIdx.x;
  const int t = threadIdx.x;
  const int w = t >> 6;         // wave 0..3
  const int l = t & 63;         // lane
  const int beg = offs[s];
  const int cnt = offs[s + 1] - beg;

  if (cnt == 0) {
    for (int u = t; u < EE; u += 256) out[(size_t)s * EE + u] = -INFINITY;
    return;
  }

  float* xsF  = (float*)dynE;        // 704 floats
  float* W12s = xsF + 704;           // 2816 floats
  float* b12s = W12s + 2816;         // 256 floats  (total 15104 B < 32768)
  ushort* y1E = dynE;

  // per-thread constants
  float b4v[6];
  #pragma unroll
  for (int ni = 0; ni < 6; ++ni) b4v[ni] = b4[w * 96 + ni * 16 + (l & 15)];
  float gp[2][2][2];
  #pragma unroll
  for (int hf = 0; hf < 2; ++hf)
    #pragma unroll
    for (int q = 0; q < 2; ++q)
      #pragma unroll
      for (int ni = 0; ni < 2; ++ni)
        gp[hf][q][ni] = gpartG[(size_t)s * H3 + hf * 256 + w * 64 + q * 32 + ni * 16 + (l & 15)];

  float om[6];
  #pragma unroll
  for (int ni = 0; ni < 6; ++ni) om[ni] = -INFINITY;

  for (int mt = 0; mt * 64 < cnt; ++mt) {
    const int mbeg = beg + mt * 64;
    const int mrem = min(64, cnt - mt * 64);

    __syncthreads();   // prev tile's hsE/y1E readers done
    // stage x rows + folded weights into overlay region
    for (int u = t; u < 704; u += 256) {
      int p = u / NFEAT, f = u - p * NFEAT;
      xsF[u] = (p < mrem) ? x[(size_t)perm[mbeg + p] * NFEAT + f] : 0.f;
    }
    for (int u = t; u < 2816; u += 256) W12s[u] = W12[u];
    b12s[t] = b12[t];
    __syncthreads();

    // h-compute: 8 granules/thread, each 8 channels of one row
    #pragma unroll
    for (int i = 0; i < 8; ++i) {
      int u = i * 256 + t;
      int row = u >> 5, gran = u & 31;
      uint4 pkt;
      if (row < mrem) {
        float acc[8];
        int cb = gran * 8;
        #pragma unroll
        for (int cj = 0; cj < 8; ++cj) acc[cj] = b12s[cb + cj];
        #pragma unroll
        for (int f = 0; f < NFEAT; ++f) {
          float xv = xsF[row * NFEAT + f];
          #pragma unroll
          for (int cj = 0; cj < 8; ++cj) acc[cj] += W12s[(cb + cj) * NFEAT + f] * xv;
        }
        pkt.x = (unsigned)f2bf(acc[0]) | ((unsigned)f2bf(acc[1]) << 16);
        pkt.y = (unsigned)f2bf(acc[2]) | ((unsigned)f2bf(acc[3]) << 16);
        pkt.z = (unsigned)f2bf(acc[4]) | ((unsigned)f2bf(acc[5]) << 16);
        pkt.w = (unsigned)f2bf(acc[6]) | ((unsigned)f2bf(acc[7]) << 16);
      } else {
        pkt.x = 0; pkt.y = 0; pkt.z = 0; pkt.w = 0;
      }
      *(uint4*)&hsE[row * 256 + ((gran ^ (row & 7)) << 3)] = pkt;
    }
    __syncthreads();   // hsE ready; overlay region free for y1

    f32x4 acc4[4][6];
    #pragma unroll
    for (int mi = 0; mi < 4; ++mi)
      #pragma unroll
      for (int ni = 0; ni < 6; ++ni)
        acc4[mi][ni] = (f32x4){0.f, 0.f, 0.f, 0.f};

    #pragma unroll
    for (int hf = 0; hf < 2; ++hf) {
      if (hf == 1) __syncthreads();   // layer4-half0 done reading y1E

      // ---- layer3 (this half): 2 quarters of 32 cols per wave ----
      #pragma unroll
      for (int q = 0; q < 2; ++q) {
        f32x4 acc3[4][2];
        #pragma unroll
        for (int mi = 0; mi < 4; ++mi)
          #pragma unroll
          for (int ni = 0; ni < 2; ++ni)
            acc3[mi][ni] = (f32x4){0.f, 0.f, 0.f, 0.f};

        for (int ks = 0; ks < 8; ++ks) {
          short8 a[4];
          #pragma unroll
          for (int mi = 0; mi < 4; ++mi) {
            int row = mi * 16 + (l & 15);
            int g = ks * 4 + (l >> 4);
            a[mi] = *(const short8*)&hsE[row * 256 + ((g ^ (row & 7)) << 3)];
          }
          short8 b[2];
          #pragma unroll
          for (int ni = 0; ni < 2; ++ni) {
            int nt = hf * 16 + w * 4 + q * 2 + ni;
            b[ni] = *(const short8*)&W3hP[(size_t)((ks * 32 + nt) * 64 + l) * 8];
          }
          #pragma unroll
          for (int mi = 0; mi < 4; ++mi)
            #pragma unroll
            for (int ni = 0; ni < 2; ++ni)
              acc3[mi][ni] = __builtin_amdgcn_mfma_f32_16x16x32_bf16(a[mi], b[ni], acc3[mi][ni], 0, 0, 0);
        }
        // bias + relu -> y1E (bf16, swizzled)
        #pragma unroll
        for (int mi = 0; mi < 4; ++mi)
          #pragma unroll
          for (int ni = 0; ni < 2; ++ni) {
            int colh = w * 64 + q * 32 + ni * 16 + (l & 15);   // col within half
            float gpv = gp[hf][q][ni];
            #pragma unroll
            for (int r = 0; r < 4; ++r) {
              int row = mi * 16 + (l >> 4) * 4 + r;
              float v = fmaxf(acc3[mi][ni][r] + gpv, 0.f);
              y1E[row * 256 + (((colh >> 3) ^ (row & 7)) << 3) + (colh & 7)] = f2bf(v);
            }
          }
      }
      __syncthreads();   // y1E half ready

      // ---- layer4 partial-K for this half ----
      for (int ks = 0; ks < 8; ++ks) {
        short8 a[4];
        #pragma unroll
        for (int mi = 0; mi < 4; ++mi) {
          int row = mi * 16 + (l & 15);
          int g = ks * 4 + (l >> 4);
          a[mi] = *(const short8*)&y1E[row * 256 + ((g ^ (row & 7)) << 3)];
        }
        short8 b[6];
        #pragma unroll
        for (int ni = 0; ni < 6; ++ni) {
          int ksg = hf * 8 + ks;
          b[ni] = *(const short8*)&W4P[(size_t)((ksg * 24 + w * 6 + ni) * 64 + l) * 8];
        }
        #pragma unroll
        for (int mi = 0; mi < 4; ++mi)
          #pragma unroll
          for (int ni = 0; ni < 6; ++ni)
            acc4[mi][ni] = __builtin_amdgcn_mfma_f32_16x16x32_bf16(a[mi], b[ni], acc4[mi][ni], 0, 0, 0);
      }
    }

    // masked segment-max update
    #pragma unroll
    for (int mi = 0; mi < 4; ++mi)
      #pragma unroll
      for (int ni = 0; ni < 6; ++ni)
        #pragma unroll
        for (int r = 0; r < 4; ++r) {
          int rowl = mt * 64 + mi * 16 + (l >> 4) * 4 + r;
          if (rowl < cnt) om[ni] = fmaxf(om[ni], acc4[mi][ni][r] + b4v[ni]);
        }
  }

  // cross-lane reduce (lanes sharing same col: l, l^16, l^32, l^48) and write
  #pragma unroll
  for (int ni = 0; ni < 6; ++ni) {
    om[ni] = fmaxf(om[ni], __shfl_xor(om[ni], 16));
    om[ni] = fmaxf(om[ni], __shfl_xor(om[ni], 32));
  }
  if (l < 16) {
    #pragma unroll
    for (int ni = 0; ni < 6; ++ni)
      out[(size_t)s * EE + w * 96 + ni * 16 + l] = om[ni];
  }
}

extern "C" void kernel_launch(void* const* d_in, const int* in_sizes, int n_in,
                              void* d_out, int out_size, void* d_ws, size_t ws_size,
                              hipStream_t stream) {
  (void)in_sizes; (void)n_in; (void)out_size; (void)ws_size;
  const float* x    = (const float*)d_in[0];
  const int*   sidx = (const int*)d_in[1];
  const float* W1   = (const float*)d_in[2];
  const float* b1   = (const float*)d_in[3];
  const float* W2   = (const float*)d_in[4];
  const float* b2   = (const float*)d_in[5];
  const float* W3   = (const float*)d_in[6];
  const float* b3   = (const float*)d_in[7];
  const float* W4   = (const float*)d_in[8];
  const float* b4   = (const float*)d_in[9];
  float* out = (float*)d_out;

  char* ws = (char*)d_ws;
  size_t off = 0;
  auto alloc = [&](size_t bytes) {
    void* p = ws + off;
    off = (off + bytes + 255) & ~(size_t)255;
    return p;
  };
  int*    counts = (int*)alloc(NSEG * 4);
  int*    cursor = (int*)alloc(NSEG * 4);
  int*    offs   = (int*)alloc((NSEG + 1) * 4);
  int*    perm   = (int*)alloc((size_t)NPTS * 4);
  float*  W12    = (float*)alloc(H2 * NFEAT * 4);
  float*  b12    = (float*)alloc(H2 * 4);
  float*  W3gT   = (float*)alloc((size_t)H2 * H3 * 4);        // 512 KB
  ushort* W3hP   = (ushort*)alloc((size_t)131072 * 2);        // 256 KB
  ushort* W4P    = (ushort*)alloc((size_t)196608 * 2);        // 384 KB
  float*  gpartG = (float*)alloc((size_t)NSEG * H3 * 4);      // 4 MB

  zero_counts<<<(NSEG + 255) / 256, 256, 0, stream>>>(counts, cursor);
  const int preptotal = 150528 + 24576;
  prep_weights<<<(preptotal + 255) / 256, 256, 0, stream>>>(W1, b1, W2, b2, W3, W4,
                                                            W12, b12, W3gT, W3hP, W4P);
  hist_kernel<<<(NPTS + 255) / 256, 256, 0, stream>>>(sidx, counts);
  scan_kernel<<<1, 1024, 0, stream>>>(counts, offs);
  scatter_kernel<<<(NPTS + 255) / 256, 256, 0, stream>>>(sidx, offs, cursor, perm);
  seg_kernel<<<NSEG, 256, 0, stream>>>(x, perm, offs, W12, b12, W3gT, b3, gpartG);
  main_kernel<<<NSEG, 256, 0, stream>>>(x, perm, offs, W12, b12, W3hP, W4P, gpartG, b4, out);
}

// Round 3
// 1242.828 us; speedup vs baseline: 5.1114x; 1.7727x over previous
//
#include <hip/hip_runtime.h>
#include <hip/hip_bf16.h>
#include <math.h>

#define BB    4
#define NN    100000
#define NFEAT 11
#define NSP   512
#define NSEG  (BB*NSP)     // 2048
#define NPTS  (BB*NN)      // 400000
#define H2    256
#define H3    512
#define EE    384
#define MT    128          // M-tile rows (NPTS % MT == 0)
#define MAXL  16           // max distinct segments per tile (fast path)
#define ENCNI 0x007FFFFFu  // enc(-inf)

typedef __attribute__((ext_vector_type(8))) short short8;
typedef __attribute__((ext_vector_type(4))) float f32x4;

__device__ __forceinline__ ushort f2bf(float f) {
  unsigned u = __builtin_bit_cast(unsigned, f);
  unsigned r = (u + 0x7FFFu + ((u >> 16) & 1u)) >> 16;
  return (ushort)r;
}
__device__ __forceinline__ unsigned encf(float f) {
  unsigned u = __builtin_bit_cast(unsigned, f);
  return u ^ ((unsigned)((int)u >> 31) | 0x80000000u);
}
__device__ __forceinline__ float decf(unsigned e) {
  unsigned u = (e & 0x80000000u) ? (e ^ 0x80000000u) : ~e;
  return __builtin_bit_cast(float, u);
}

// ---------------- sort pipeline (validated R1) ----------------
__global__ void zero_counts(int* __restrict__ counts, int* __restrict__ cursor) {
  int i = blockIdx.x * blockDim.x + threadIdx.x;
  if (i < NSEG) { counts[i] = 0; cursor[i] = 0; }
}

__global__ void hist_kernel(const int* __restrict__ sidx, int* __restrict__ counts) {
  int i = blockIdx.x * blockDim.x + threadIdx.x;
  if (i < NPTS) {
    int seg = sidx[i] + (i / NN) * NSP;
    atomicAdd(&counts[seg], 1);
  }
}

__global__ void scan_kernel(const int* __restrict__ counts, int* __restrict__ offs) {
  __shared__ int buf[1024];
  int t = threadIdx.x;
  int c0 = counts[2 * t], c1 = counts[2 * t + 1];
  int s = c0 + c1;
  buf[t] = s;
  __syncthreads();
  for (int d = 1; d < 1024; d <<= 1) {
    int add = (t >= d) ? buf[t - d] : 0;
    __syncthreads();
    buf[t] += add;
    __syncthreads();
  }
  int incl = buf[t];
  int excl = incl - s;
  offs[2 * t] = excl;
  offs[2 * t + 1] = excl + c0;
  if (t == 1023) offs[2048] = incl;
}

__global__ void scatter_kernel(const int* __restrict__ sidx, const int* __restrict__ offs,
                               int* __restrict__ cursor, int* __restrict__ perm) {
  int i = blockIdx.x * blockDim.x + threadIdx.x;
  if (i < NPTS) {
    int seg = sidx[i] + (i / NN) * NSP;
    int pos = offs[seg] + atomicAdd(&cursor[seg], 1);
    perm[pos] = i;
  }
}

// ---------------- weight prep (packing formats validated R2) ----------------
__global__ void prep_weights(const float* __restrict__ W1, const float* __restrict__ b1,
                             const float* __restrict__ W2, const float* __restrict__ b2,
                             const float* __restrict__ W3, const float* __restrict__ W4,
                             float* __restrict__ W12, float* __restrict__ b12,
                             float* __restrict__ W3gT, ushort* __restrict__ W3hP,
                             ushort* __restrict__ W4P) {
  int u = blockIdx.x * blockDim.x + threadIdx.x;
  if (u < H2 * NFEAT) {                           // 2816
    int c = u / NFEAT, f = u - c * NFEAT;
    float acc = 0.f;
    for (int j = 0; j < 128; ++j) acc += W2[c * 128 + j] * W1[j * NFEAT + f];
    W12[u] = acc;
  } else if (u < 3072) {                          // b12
    int c = u - H2 * NFEAT;
    float acc = b2[c];
    for (int j = 0; j < 128; ++j) acc += W2[c * 128 + j] * b1[j];
    b12[c] = acc;
  } else if (u < 3072 + 131072) {                 // W3gT fp32 [c][o]
    int v = u - 3072;
    int c = v >> 9, o = v & 511;
    W3gT[v] = W3[o * H3 + c];
  } else if (u < 134144 + 16384) {                // W3hP
    int v = u - 134144;
    int ks = v >> 11, rem = v & 2047;
    int nt = rem >> 6, l = rem & 63;
    int n = nt * 16 + (l & 15);
    #pragma unroll
    for (int j = 0; j < 8; ++j) {
      int k = ks * 32 + (l >> 4) * 8 + j;
      W3hP[(size_t)v * 8 + j] = f2bf(W3[n * H3 + H2 + k]);
    }
  } else if (u < 150528 + 24576) {                // W4P
    int v = u - 150528;
    int ks = v / 1536, rem = v - ks * 1536;
    int nt = rem >> 6, l = rem & 63;
    int n = nt * 16 + (l & 15);
    #pragma unroll
    for (int j = 0; j < 8; ++j) {
      int k = ks * 32 + (l >> 4) * 8 + j;
      W4P[(size_t)v * 8 + j] = f2bf(W4[n * H3 + k]);
    }
  }
}

// ---------------- per-segment: gmax only (fp32) ----------------
__global__ __launch_bounds__(256) void seg_kernel(
    const float* __restrict__ x, const int* __restrict__ perm,
    const int* __restrict__ offs,
    const float* __restrict__ W12, const float* __restrict__ b12,
    float* __restrict__ gmaxG) {
  __shared__ float W12s[H2 * NFEAT];
  __shared__ float b12s[H2];
  __shared__ float xs[64 * NFEAT];

  const int s = blockIdx.x;
  const int t = threadIdx.x;
  const int beg = offs[s];
  const int cnt = offs[s + 1] - beg;
  if (cnt == 0) return;   // empty seg: gmax unused downstream

  for (int u = t; u < H2 * NFEAT; u += 256) W12s[u] = W12[u];
  b12s[t] = b12[t];
  __syncthreads();

  float gm = -INFINITY;
  for (int base = 0; base < cnt; base += 64) {
    int m = min(64, cnt - base);
    __syncthreads();
    for (int u = t; u < m * NFEAT; u += 256) {
      int p = u / NFEAT, f = u - p * NFEAT;
      xs[u] = x[(size_t)perm[beg + base + p] * NFEAT + f];
    }
    __syncthreads();
    for (int p = 0; p < m; ++p) {
      float acc = b12s[t];
      #pragma unroll
      for (int f = 0; f < NFEAT; ++f) acc += W12s[t * NFEAT + f] * xs[p * NFEAT + f];
      gm = fmaxf(gm, acc);
    }
  }
  gmaxG[(size_t)s * H2 + t] = gm;
}

// ---------------- gpart = b3 + gmax @ W3g^T (fp32, flat) ----------------
__global__ __launch_bounds__(256) void gpart_kernel(
    const float* __restrict__ gmaxG, const float* __restrict__ W3gT,
    const float* __restrict__ b3, float* __restrict__ gpartG) {
  __shared__ float gm[64 * 256];   // 64 KB
  const int t = threadIdx.x;
  const int b = blockIdx.x;        // 32 blocks x 64 segs
  for (int u = t; u < 64 * 256; u += 256) gm[u] = gmaxG[(size_t)b * 64 * 256 + u];
  __syncthreads();
  const float bb0 = b3[t], bb1 = b3[t + 256];
  for (int grp = 0; grp < 4; ++grp) {
    float a0[16], a1[16];
    #pragma unroll
    for (int sg = 0; sg < 16; ++sg) { a0[sg] = bb0; a1[sg] = bb1; }
    for (int c = 0; c < 256; ++c) {
      float w0 = W3gT[c * 512 + t], w1 = W3gT[c * 512 + t + 256];
      #pragma unroll
      for (int sg = 0; sg < 16; ++sg) {
        float gv = gm[(grp * 16 + sg) * 256 + c];
        a0[sg] += w0 * gv; a1[sg] += w1 * gv;
      }
    }
    #pragma unroll
    for (int sg = 0; sg < 16; ++sg) {
      size_t s = (size_t)b * 64 + grp * 16 + sg;
      gpartG[s * 512 + t] = a0[sg];
      gpartG[s * 512 + t + 256] = a1[sg];
    }
  }
}

__global__ void init_enc_kernel(unsigned* __restrict__ enc) {
  int i = blockIdx.x * 256 + threadIdx.x;
  if (i < NSEG * EE) enc[i] = ENCNI;
}

__global__ void finalize_kernel(const unsigned* __restrict__ enc, float* __restrict__ out) {
  int i = blockIdx.x * 256 + threadIdx.x;
  if (i < NSEG * EE) out[i] = decf(enc[i]);
}

// ---------------- main: flat-M fused MFMA, MT=128 rows, 8 waves ----------------
__global__ __launch_bounds__(512, 2) void main_kernel(
    const float* __restrict__ x, const int* __restrict__ perm,
    const int* __restrict__ sidx,
    const float* __restrict__ W12, const float* __restrict__ b12,
    const ushort* __restrict__ W3hP, const ushort* __restrict__ W4P,
    const float* __restrict__ gpartG, const float* __restrict__ b4,
    unsigned* __restrict__ out_enc) {
  __shared__ __align__(16) ushort hsE[MT * 256];    // 64 KB  h tile (bf16, swizzled)
  __shared__ __align__(16) ushort regB[MT * 256];   // 64 KB  overlay: xs/W12/b12 -> y1 half -> obuf
  __shared__ float gpartL[MAXL * 256];              // 16 KB
  __shared__ int segdL[MT];
  __shared__ int s_loS, nlocS;

  const int t = threadIdx.x;
  const int w = t >> 6;        // wave 0..7
  const int l = t & 63;
  const int mbeg = blockIdx.x * MT;
  const int nvalid = min(MT, NPTS - mbeg);

  float* xsF  = (float*)regB;          // 1408 floats
  float* W12s = xsF + 1408;            // 2816 floats
  float* b12s = W12s + 2816;           // 256 floats
  ushort* y1E = regB;
  unsigned* obuf = (unsigned*)regB;

  // ---- stage x, folded weights, per-row segment ids ----
  for (int u = t; u < MT * NFEAT; u += 512) {
    int p = u / NFEAT, f = u - p * NFEAT;
    xsF[u] = (p < nvalid) ? x[(size_t)perm[mbeg + p] * NFEAT + f] : 0.f;
  }
  for (int u = t; u < 2816; u += 512) W12s[u] = W12[u];
  if (t < 256) b12s[t] = b12[t];
  if (t < MT) {
    int sg = 0;
    if (t < nvalid) {
      int i = perm[mbeg + t];
      sg = sidx[i] + (i / NN) * NSP;
    }
    segdL[t] = sg;
  }
  __syncthreads();
  if (t == 0) {
    s_loS = segdL[0];
    nlocS = segdL[nvalid - 1] - segdL[0] + 1;
  }
  __syncthreads();
  const int s_lo = s_loS;
  const int nloc = nlocS;
  const bool fb = (nloc > MAXL);    // pathological fallback
  if (t < MT && t >= nvalid) segdL[t] = s_lo;

  // ---- h compute -> hsE (bf16, swizzled) ----
  #pragma unroll
  for (int i = 0; i < 8; ++i) {
    int u = i * 512 + t;
    int row = u >> 5, gran = u & 31;
    uint4 pkt = {0, 0, 0, 0};
    if (row < nvalid) {
      float acc[8];
      int cb = gran * 8;
      #pragma unroll
      for (int cj = 0; cj < 8; ++cj) acc[cj] = b12s[cb + cj];
      #pragma unroll
      for (int f = 0; f < NFEAT; ++f) {
        float xv = xsF[row * NFEAT + f];
        #pragma unroll
        for (int cj = 0; cj < 8; ++cj) acc[cj] += W12s[(cb + cj) * NFEAT + f] * xv;
      }
      pkt.x = (unsigned)f2bf(acc[0]) | ((unsigned)f2bf(acc[1]) << 16);
      pkt.y = (unsigned)f2bf(acc[2]) | ((unsigned)f2bf(acc[3]) << 16);
      pkt.z = (unsigned)f2bf(acc[4]) | ((unsigned)f2bf(acc[5]) << 16);
      pkt.w = (unsigned)f2bf(acc[6]) | ((unsigned)f2bf(acc[7]) << 16);
    }
    *(uint4*)&hsE[row * 256 + ((gran ^ (row & 7)) << 3)] = pkt;
  }
  __syncthreads();   // hsE ready; regB overlay free; segdL fixed

  float b4v[3];
  #pragma unroll
  for (int ni = 0; ni < 3; ++ni) b4v[ni] = b4[w * 48 + ni * 16 + (l & 15)];

  f32x4 acc4[8][3];
  #pragma unroll
  for (int mi = 0; mi < 8; ++mi)
    #pragma unroll
    for (int ni = 0; ni < 3; ++ni)
      acc4[mi][ni] = (f32x4){0.f, 0.f, 0.f, 0.f};

  #pragma unroll
  for (int hf = 0; hf < 2; ++hf) {
    // stage this half's gpart rows for the tile's local segments
    if (!fb) {
      for (int u = t; u < nloc * 256; u += 512) {
        int sg = u >> 8, c = u & 255;
        gpartL[u] = gpartG[(size_t)(s_lo + sg) * 512 + hf * 256 + c];
      }
    }

    // ---- layer3 (this half): wave w -> 2 ntiles (32 cols) ----
    f32x4 acc3[8][2];
    #pragma unroll
    for (int mi = 0; mi < 8; ++mi)
      #pragma unroll
      for (int ni = 0; ni < 2; ++ni)
        acc3[mi][ni] = (f32x4){0.f, 0.f, 0.f, 0.f};

    #pragma unroll
    for (int ks = 0; ks < 8; ++ks) {
      short8 bfr[2];
      #pragma unroll
      for (int ni = 0; ni < 2; ++ni) {
        int nt = hf * 16 + w * 2 + ni;
        bfr[ni] = *(const short8*)&W3hP[(size_t)((ks * 32 + nt) * 64 + l) * 8];
      }
      #pragma unroll
      for (int mi = 0; mi < 8; ++mi) {
        int row = mi * 16 + (l & 15);
        int g = ks * 4 + (l >> 4);
        short8 a = *(const short8*)&hsE[row * 256 + ((g ^ (row & 7)) << 3)];
        acc3[mi][0] = __builtin_amdgcn_mfma_f32_16x16x32_bf16(a, bfr[0], acc3[mi][0], 0, 0, 0);
        acc3[mi][1] = __builtin_amdgcn_mfma_f32_16x16x32_bf16(a, bfr[1], acc3[mi][1], 0, 0, 0);
      }
    }
    __syncthreads();   // gpartL staged; previous regB readers done

    // ---- bias(gpart) + relu -> y1E (bf16, swizzled) ----
    #pragma unroll
    for (int mi = 0; mi < 8; ++mi)
      #pragma unroll
      for (int ni = 0; ni < 2; ++ni) {
        int colh = w * 32 + ni * 16 + (l & 15);
        #pragma unroll
        for (int r = 0; r < 4; ++r) {
          int row = mi * 16 + (l >> 4) * 4 + r;
          int sg = segdL[row];
          float bias = fb ? gpartG[(size_t)sg * 512 + hf * 256 + colh]
                          : gpartL[(sg - s_lo) * 256 + colh];
          float v = fmaxf(acc3[mi][ni][r] + bias, 0.f);
          y1E[row * 256 + (((colh >> 3) ^ (row & 7)) << 3) + (colh & 7)] = f2bf(v);
        }
      }
    __syncthreads();   // y1E half ready

    // ---- layer4 partial-K: wave w -> 3 ntiles (48 cols) ----
    #pragma unroll
    for (int ks = 0; ks < 8; ++ks) {
      short8 bfr[3];
      #pragma unroll
      for (int ni = 0; ni < 3; ++ni) {
        int ksg = hf * 8 + ks;
        bfr[ni] = *(const short8*)&W4P[(size_t)((ksg * 24 + w * 3 + ni) * 64 + l) * 8];
      }
      #pragma unroll
      for (int mi = 0; mi < 8; ++mi) {
        int row = mi * 16 + (l & 15);
        int g = ks * 4 + (l >> 4);
        short8 a = *(const short8*)&y1E[row * 256 + ((g ^ (row & 7)) << 3)];
        acc4[mi][0] = __builtin_amdgcn_mfma_f32_16x16x32_bf16(a, bfr[0], acc4[mi][0], 0, 0, 0);
        acc4[mi][1] = __builtin_amdgcn_mfma_f32_16x16x32_bf16(a, bfr[1], acc4[mi][1], 0, 0, 0);
        acc4[mi][2] = __builtin_amdgcn_mfma_f32_16x16x32_bf16(a, bfr[2], acc4[mi][2], 0, 0, 0);
      }
    }
    __syncthreads();   // layer4 done reading y1E (before rewrite / obuf reuse)
  }

  // ---- epilogue: segment-max via LDS enc-atomicMax then global ----
  if (!fb) {
    for (int u = t; u < nloc * EE; u += 512) obuf[u] = ENCNI;
    __syncthreads();
    #pragma unroll
    for (int mi = 0; mi < 8; ++mi)
      #pragma unroll
      for (int ni = 0; ni < 3; ++ni) {
        int col = w * 48 + ni * 16 + (l & 15);
        #pragma unroll
        for (int r = 0; r < 4; ++r) {
          int row = mi * 16 + (l >> 4) * 4 + r;
          if (row < nvalid) {
            unsigned e = encf(acc4[mi][ni][r] + b4v[ni]);
            atomicMax(&obuf[(segdL[row] - s_lo) * EE + col], e);
          }
        }
      }
    __syncthreads();
    for (int u = t; u < nloc * EE; u += 512) {
      unsigned e = obuf[u];
      if (e != ENCNI)
        atomicMax(&out_enc[(size_t)(s_lo + u / EE) * EE + (u % EE)], e);
    }
  } else {
    #pragma unroll
    for (int mi = 0; mi < 8; ++mi)
      #pragma unroll
      for (int ni = 0; ni < 3; ++ni) {
        int col = w * 48 + ni * 16 + (l & 15);
        #pragma unroll
        for (int r = 0; r < 4; ++r) {
          int row = mi * 16 + (l >> 4) * 4 + r;
          if (row < nvalid) {
            unsigned e = encf(acc4[mi][ni][r] + b4v[ni]);
            atomicMax(&out_enc[(size_t)segdL[row] * EE + col], e);
          }
        }
      }
  }
}

extern "C" void kernel_launch(void* const* d_in, const int* in_sizes, int n_in,
                              void* d_out, int out_size, void* d_ws, size_t ws_size,
                              hipStream_t stream) {
  (void)in_sizes; (void)n_in; (void)out_size; (void)ws_size;
  const float* x    = (const float*)d_in[0];
  const int*   sidx = (const int*)d_in[1];
  const float* W1   = (const float*)d_in[2];
  const float* b1   = (const float*)d_in[3];
  const float* W2   = (const float*)d_in[4];
  const float* b2   = (const float*)d_in[5];
  const float* W3   = (const float*)d_in[6];
  const float* b3   = (const float*)d_in[7];
  const float* W4   = (const float*)d_in[8];
  const float* b4   = (const float*)d_in[9];
  float* out = (float*)d_out;

  char* ws = (char*)d_ws;
  size_t off = 0;
  auto alloc = [&](size_t bytes) {
    void* p = ws + off;
    off = (off + bytes + 255) & ~(size_t)255;
    return p;
  };
  int*      counts  = (int*)alloc(NSEG * 4);
  int*      cursor  = (int*)alloc(NSEG * 4);
  int*      offs    = (int*)alloc((NSEG + 1) * 4);
  int*      perm    = (int*)alloc((size_t)NPTS * 4);
  float*    W12     = (float*)alloc(H2 * NFEAT * 4);
  float*    b12     = (float*)alloc(H2 * 4);
  float*    W3gT    = (float*)alloc((size_t)H2 * H3 * 4);     // 512 KB
  ushort*   W3hP    = (ushort*)alloc((size_t)131072 * 2);     // 256 KB
  ushort*   W4P     = (ushort*)alloc((size_t)196608 * 2);     // 384 KB
  float*    gmaxG   = (float*)alloc((size_t)NSEG * H2 * 4);   // 2 MB
  float*    gpartG  = (float*)alloc((size_t)NSEG * H3 * 4);   // 4 MB
  unsigned* out_enc = (unsigned*)alloc((size_t)NSEG * EE * 4);// 3 MB

  zero_counts<<<(NSEG + 255) / 256, 256, 0, stream>>>(counts, cursor);
  const int preptotal = 150528 + 24576;
  prep_weights<<<(preptotal + 255) / 256, 256, 0, stream>>>(W1, b1, W2, b2, W3, W4,
                                                            W12, b12, W3gT, W3hP, W4P);
  hist_kernel<<<(NPTS + 255) / 256, 256, 0, stream>>>(sidx, counts);
  scan_kernel<<<1, 1024, 0, stream>>>(counts, offs);
  scatter_kernel<<<(NPTS + 255) / 256, 256, 0, stream>>>(sidx, offs, cursor, perm);
  seg_kernel<<<NSEG, 256, 0, stream>>>(x, perm, offs, W12, b12, gmaxG);
  gpart_kernel<<<NSEG / 64, 256, 0, stream>>>(gmaxG, W3gT, b3, gpartG);
  init_enc_kernel<<<(NSEG * EE + 255) / 256, 256, 0, stream>>>(out_enc);
  main_kernel<<<NPTS / MT, 512, 0, stream>>>(x, perm, sidx, W12, b12,
                                             W3hP, W4P, gpartG, b4, out_enc);
  finalize_kernel<<<(NSEG * EE + 255) / 256, 256, 0, stream>>>(out_enc, out);
}

// Round 5
// 992.131 us; speedup vs baseline: 6.4030x; 1.2527x over previous
//
#include <hip/hip_runtime.h>
#include <hip/hip_bf16.h>
#include <math.h>

#define BB    4
#define NN    100000
#define NFEAT 11
#define NSP   512
#define NSEG  (BB*NSP)     // 2048
#define NPTS  (BB*NN)      // 400000
#define H2    256
#define H3    512
#define EE    384
#define MT    128          // M-tile rows (NPTS % MT == 0)
#define MAXL  16           // max distinct segments per tile (fast path)
#define ENCNI 0x007FFFFFu  // enc(-inf)

typedef __attribute__((ext_vector_type(8))) short short8;
typedef __attribute__((ext_vector_type(4))) float f32x4;

__device__ __forceinline__ ushort f2bf(float f) {
  unsigned u = __builtin_bit_cast(unsigned, f);
  unsigned r = (u + 0x7FFFu + ((u >> 16) & 1u)) >> 16;
  return (ushort)r;
}
__device__ __forceinline__ unsigned encf(float f) {
  unsigned u = __builtin_bit_cast(unsigned, f);
  return u ^ ((unsigned)((int)u >> 31) | 0x80000000u);
}
__device__ __forceinline__ float decf(unsigned e) {
  unsigned u = (e & 0x80000000u) ? (e ^ 0x80000000u) : ~e;
  return __builtin_bit_cast(float, u);
}

// ---------------- sort pipeline (validated R1) ----------------
__global__ void zero_counts(int* __restrict__ counts, int* __restrict__ cursor) {
  int i = blockIdx.x * blockDim.x + threadIdx.x;
  if (i < NSEG) { counts[i] = 0; cursor[i] = 0; }
}

__global__ void hist_kernel(const int* __restrict__ sidx, int* __restrict__ counts) {
  int i = blockIdx.x * blockDim.x + threadIdx.x;
  if (i < NPTS) {
    int seg = sidx[i] + (i / NN) * NSP;
    atomicAdd(&counts[seg], 1);
  }
}

__global__ void scan_kernel(const int* __restrict__ counts, int* __restrict__ offs) {
  __shared__ int buf[1024];
  int t = threadIdx.x;
  int c0 = counts[2 * t], c1 = counts[2 * t + 1];
  int s = c0 + c1;
  buf[t] = s;
  __syncthreads();
  for (int d = 1; d < 1024; d <<= 1) {
    int add = (t >= d) ? buf[t - d] : 0;
    __syncthreads();
    buf[t] += add;
    __syncthreads();
  }
  int incl = buf[t];
  int excl = incl - s;
  offs[2 * t] = excl;
  offs[2 * t + 1] = excl + c0;
  if (t == 1023) offs[2048] = incl;
}

__global__ void scatter_kernel(const int* __restrict__ sidx, const int* __restrict__ offs,
                               int* __restrict__ cursor, int* __restrict__ perm) {
  int i = blockIdx.x * blockDim.x + threadIdx.x;
  if (i < NPTS) {
    int seg = sidx[i] + (i / NN) * NSP;
    int pos = offs[seg] + atomicAdd(&cursor[seg], 1);
    perm[pos] = i;
  }
}

// ---------------- weight prep (packing formats validated R2/R3) ----------------
__global__ void prep_weights(const float* __restrict__ W1, const float* __restrict__ b1,
                             const float* __restrict__ W2, const float* __restrict__ b2,
                             const float* __restrict__ W3, const float* __restrict__ W4,
                             float* __restrict__ W12, float* __restrict__ b12,
                             float* __restrict__ W3gT, ushort* __restrict__ W3hP,
                             ushort* __restrict__ W4P) {
  int u = blockIdx.x * blockDim.x + threadIdx.x;
  if (u < H2 * NFEAT) {                           // 2816
    int c = u / NFEAT, f = u - c * NFEAT;
    float acc = 0.f;
    for (int j = 0; j < 128; ++j) acc += W2[c * 128 + j] * W1[j * NFEAT + f];
    W12[u] = acc;
  } else if (u < 3072) {                          // b12
    int c = u - H2 * NFEAT;
    float acc = b2[c];
    for (int j = 0; j < 128; ++j) acc += W2[c * 128 + j] * b1[j];
    b12[c] = acc;
  } else if (u < 3072 + 131072) {                 // W3gT fp32 [c][o]
    int v = u - 3072;
    int c = v >> 9, o = v & 511;
    W3gT[v] = W3[o * H3 + c];
  } else if (u < 134144 + 16384) {                // W3hP
    int v = u - 134144;
    int ks = v >> 11, rem = v & 2047;
    int nt = rem >> 6, l = rem & 63;
    int n = nt * 16 + (l & 15);
    #pragma unroll
    for (int j = 0; j < 8; ++j) {
      int k = ks * 32 + (l >> 4) * 8 + j;
      W3hP[(size_t)v * 8 + j] = f2bf(W3[n * H3 + H2 + k]);
    }
  } else if (u < 150528 + 24576) {                // W4P
    int v = u - 150528;
    int ks = v / 1536, rem = v - ks * 1536;
    int nt = rem >> 6, l = rem & 63;
    int n = nt * 16 + (l & 15);
    #pragma unroll
    for (int j = 0; j < 8; ++j) {
      int k = ks * 32 + (l >> 4) * 8 + j;
      W4P[(size_t)v * 8 + j] = f2bf(W4[n * H3 + k]);
    }
  }
}

// ---------------- per-segment: gmax only (fp32) ----------------
__global__ __launch_bounds__(256) void seg_kernel(
    const float* __restrict__ x, const int* __restrict__ perm,
    const int* __restrict__ offs,
    const float* __restrict__ W12, const float* __restrict__ b12,
    float* __restrict__ gmaxG) {
  __shared__ float W12s[H2 * NFEAT];
  __shared__ float b12s[H2];
  __shared__ float xs[64 * NFEAT];

  const int s = blockIdx.x;
  const int t = threadIdx.x;
  const int beg = offs[s];
  const int cnt = offs[s + 1] - beg;
  if (cnt == 0) return;

  for (int u = t; u < H2 * NFEAT; u += 256) W12s[u] = W12[u];
  b12s[t] = b12[t];
  __syncthreads();

  float gm = -INFINITY;
  for (int base = 0; base < cnt; base += 64) {
    int m = min(64, cnt - base);
    __syncthreads();
    for (int u = t; u < m * NFEAT; u += 256) {
      int p = u / NFEAT, f = u - p * NFEAT;
      xs[u] = x[(size_t)perm[beg + base + p] * NFEAT + f];
    }
    __syncthreads();
    for (int p = 0; p < m; ++p) {
      float acc = b12s[t];
      #pragma unroll
      for (int f = 0; f < NFEAT; ++f) acc += W12s[t * NFEAT + f] * xs[p * NFEAT + f];
      gm = fmaxf(gm, acc);
    }
  }
  gmaxG[(size_t)s * H2 + t] = gm;
}

// ---------------- gpart = b3 + gmax @ W3g^T (fp32, flat) ----------------
__global__ __launch_bounds__(256) void gpart_kernel(
    const float* __restrict__ gmaxG, const float* __restrict__ W3gT,
    const float* __restrict__ b3, float* __restrict__ gpartG) {
  __shared__ float gm[64 * 256];   // 64 KB
  const int t = threadIdx.x;
  const int b = blockIdx.x;        // 32 blocks x 64 segs
  for (int u = t; u < 64 * 256; u += 256) gm[u] = gmaxG[(size_t)b * 64 * 256 + u];
  __syncthreads();
  const float bb0 = b3[t], bb1 = b3[t + 256];
  for (int grp = 0; grp < 4; ++grp) {
    float a0[16], a1[16];
    #pragma unroll
    for (int sg = 0; sg < 16; ++sg) { a0[sg] = bb0; a1[sg] = bb1; }
    for (int c = 0; c < 256; ++c) {
      float w0 = W3gT[c * 512 + t], w1 = W3gT[c * 512 + t + 256];
      #pragma unroll
      for (int sg = 0; sg < 16; ++sg) {
        float gv = gm[(grp * 16 + sg) * 256 + c];
        a0[sg] += w0 * gv; a1[sg] += w1 * gv;
      }
    }
    #pragma unroll
    for (int sg = 0; sg < 16; ++sg) {
      size_t s = (size_t)b * 64 + grp * 16 + sg;
      gpartG[s * 512 + t] = a0[sg];
      gpartG[s * 512 + t + 256] = a1[sg];
    }
  }
}

__global__ void init_enc_kernel(unsigned* __restrict__ enc) {
  int i = blockIdx.x * 256 + threadIdx.x;
  if (i < NSEG * EE) enc[i] = ENCNI;
}

__global__ void finalize_kernel(const unsigned* __restrict__ enc, float* __restrict__ out) {
  int i = blockIdx.x * 256 + threadIdx.x;
  if (i < NSEG * EE) out[i] = decf(enc[i]);
}

// ---------------- main: flat-M fused MFMA, MT=128, 8 waves ----------------
// R5: identical to validated R3 except LDS tile addressing changed from
// [row][col^swz] (8-way ds_read_b128 conflict) to [granule][row]:
// cell(g,row) = g*1024 + row*8 ushorts. A-frag reads = 16 lanes x contiguous
// 256B per quarter-wave (conflict-free); h-writes = wave-contiguous 1KB.
__global__ __launch_bounds__(512, 2) void main_kernel(
    const float* __restrict__ x, const int* __restrict__ perm,
    const int* __restrict__ sidx,
    const float* __restrict__ W12, const float* __restrict__ b12,
    const ushort* __restrict__ W3hP, const ushort* __restrict__ W4P,
    const float* __restrict__ gpartG, const float* __restrict__ b4,
    unsigned* __restrict__ out_enc) {
  __shared__ __align__(16) ushort hsE[MT * 256];    // 64 KB  h tile [gran][row]
  __shared__ __align__(16) ushort regB[MT * 256];   // 64 KB  overlay: xs/W12/b12 -> y1 half -> obuf
  __shared__ float gpartL[MAXL * 256];              // 16 KB
  __shared__ int segdL[MT];
  __shared__ int s_loS, nlocS;

  const int t = threadIdx.x;
  const int w = t >> 6;        // wave 0..7
  const int l = t & 63;
  const int mbeg = blockIdx.x * MT;
  const int nvalid = min(MT, NPTS - mbeg);

  float* xsF  = (float*)regB;          // 1408 floats
  float* W12s = xsF + 1408;            // 2816 floats
  float* b12s = W12s + 2816;           // 256 floats
  ushort* y1E = regB;
  unsigned* obuf = (unsigned*)regB;

  // ---- stage x, folded weights, per-row segment ids ----
  for (int u = t; u < MT * NFEAT; u += 512) {
    int p = u / NFEAT, f = u - p * NFEAT;
    xsF[u] = (p < nvalid) ? x[(size_t)perm[mbeg + p] * NFEAT + f] : 0.f;
  }
  for (int u = t; u < 2816; u += 512) W12s[u] = W12[u];
  if (t < 256) b12s[t] = b12[t];
  if (t < MT) {
    int sg = 0;
    if (t < nvalid) {
      int i = perm[mbeg + t];
      sg = sidx[i] + (i / NN) * NSP;
    }
    segdL[t] = sg;
  }
  __syncthreads();
  if (t == 0) {
    s_loS = segdL[0];
    nlocS = segdL[nvalid - 1] - segdL[0] + 1;
  }
  __syncthreads();
  const int s_lo = s_loS;
  const int nloc = nlocS;
  const bool fb = (nloc > MAXL);    // pathological fallback
  if (t < MT && t >= nvalid) segdL[t] = s_lo;

  // ---- h compute -> hsE[gran][row] : gran wave-uniform, row = rr*64 + lane ----
  #pragma unroll
  for (int i = 0; i < 4; ++i) {
    int gran = i * 8 + w;          // wave-uniform -> W12s reads broadcast
    int cb = gran * 8;
    #pragma unroll
    for (int rr = 0; rr < 2; ++rr) {
      int row = rr * 64 + l;
      uint4 pkt = {0, 0, 0, 0};
      if (row < nvalid) {
        float acc[8];
        #pragma unroll
        for (int cj = 0; cj < 8; ++cj) acc[cj] = b12s[cb + cj];
        #pragma unroll
        for (int f = 0; f < NFEAT; ++f) {
          float xv = xsF[row * NFEAT + f];
          #pragma unroll
          for (int cj = 0; cj < 8; ++cj) acc[cj] += W12s[(cb + cj) * NFEAT + f] * xv;
        }
        pkt.x = (unsigned)f2bf(acc[0]) | ((unsigned)f2bf(acc[1]) << 16);
        pkt.y = (unsigned)f2bf(acc[2]) | ((unsigned)f2bf(acc[3]) << 16);
        pkt.z = (unsigned)f2bf(acc[4]) | ((unsigned)f2bf(acc[5]) << 16);
        pkt.w = (unsigned)f2bf(acc[6]) | ((unsigned)f2bf(acc[7]) << 16);
      }
      *(uint4*)&hsE[gran * 1024 + row * 8] = pkt;   // contiguous 1KB per wave-step
    }
  }
  __syncthreads();   // hsE ready; xsF (regB overlay) free; segdL fixed

  float b4v[3];
  #pragma unroll
  for (int ni = 0; ni < 3; ++ni) b4v[ni] = b4[w * 48 + ni * 16 + (l & 15)];

  f32x4 acc4[8][3];
  #pragma unroll
  for (int mi = 0; mi < 8; ++mi)
    #pragma unroll
    for (int ni = 0; ni < 3; ++ni)
      acc4[mi][ni] = (f32x4){0.f, 0.f, 0.f, 0.f};

  #pragma unroll
  for (int hf = 0; hf < 2; ++hf) {
    // stage this half's gpart rows for the tile's local segments
    if (!fb) {
      for (int u = t; u < nloc * 256; u += 512) {
        int sg = u >> 8, c = u & 255;
        gpartL[u] = gpartG[(size_t)(s_lo + sg) * 512 + hf * 256 + c];
      }
    }

    // ---- layer3 (this half): wave w -> 2 ntiles (32 cols) ----
    f32x4 acc3[8][2];
    #pragma unroll
    for (int mi = 0; mi < 8; ++mi)
      #pragma unroll
      for (int ni = 0; ni < 2; ++ni)
        acc3[mi][ni] = (f32x4){0.f, 0.f, 0.f, 0.f};

    #pragma unroll
    for (int ks = 0; ks < 8; ++ks) {
      short8 bfr[2];
      #pragma unroll
      for (int ni = 0; ni < 2; ++ni) {
        int nt = hf * 16 + w * 2 + ni;
        bfr[ni] = *(const short8*)&W3hP[(size_t)((ks * 32 + nt) * 64 + l) * 8];
      }
      #pragma unroll
      for (int mi = 0; mi < 8; ++mi) {
        short8 a = *(const short8*)&hsE[(ks * 4 + (l >> 4)) * 1024 + (mi * 16 + (l & 15)) * 8];
        acc3[mi][0] = __builtin_amdgcn_mfma_f32_16x16x32_bf16(a, bfr[0], acc3[mi][0], 0, 0, 0);
        acc3[mi][1] = __builtin_amdgcn_mfma_f32_16x16x32_bf16(a, bfr[1], acc3[mi][1], 0, 0, 0);
      }
    }
    __syncthreads();   // gpartL staged; previous regB readers done

    // ---- bias(gpart) + relu -> y1E[gran][row] ----
    #pragma unroll
    for (int mi = 0; mi < 8; ++mi)
      #pragma unroll
      for (int ni = 0; ni < 2; ++ni) {
        int colh = w * 32 + ni * 16 + (l & 15);
        #pragma unroll
        for (int r = 0; r < 4; ++r) {
          int row = mi * 16 + (l >> 4) * 4 + r;
          int sg = segdL[row];
          float bias = fb ? gpartG[(size_t)sg * 512 + hf * 256 + colh]
                          : gpartL[(sg - s_lo) * 256 + colh];
          float v = fmaxf(acc3[mi][ni][r] + bias, 0.f);
          y1E[(colh >> 3) * 1024 + row * 8 + (colh & 7)] = f2bf(v);
        }
      }
    __syncthreads();   // y1E half ready

    // ---- layer4 partial-K: wave w -> 3 ntiles (48 cols) ----
    #pragma unroll
    for (int ks = 0; ks < 8; ++ks) {
      short8 bfr[3];
      #pragma unroll
      for (int ni = 0; ni < 3; ++ni) {
        int ksg = hf * 8 + ks;
        bfr[ni] = *(const short8*)&W4P[(size_t)((ksg * 24 + w * 3 + ni) * 64 + l) * 8];
      }
      #pragma unroll
      for (int mi = 0; mi < 8; ++mi) {
        short8 a = *(const short8*)&y1E[(ks * 4 + (l >> 4)) * 1024 + (mi * 16 + (l & 15)) * 8];
        acc4[mi][0] = __builtin_amdgcn_mfma_f32_16x16x32_bf16(a, bfr[0], acc4[mi][0], 0, 0, 0);
        acc4[mi][1] = __builtin_amdgcn_mfma_f32_16x16x32_bf16(a, bfr[1], acc4[mi][1], 0, 0, 0);
        acc4[mi][2] = __builtin_amdgcn_mfma_f32_16x16x32_bf16(a, bfr[2], acc4[mi][2], 0, 0, 0);
      }
    }
    __syncthreads();   // layer4 done reading y1E (before rewrite / obuf reuse)
  }

  // ---- epilogue: segment-max via LDS enc-atomicMax then global ----
  if (!fb) {
    for (int u = t; u < nloc * EE; u += 512) obuf[u] = ENCNI;
    __syncthreads();
    #pragma unroll
    for (int mi = 0; mi < 8; ++mi)
      #pragma unroll
      for (int ni = 0; ni < 3; ++ni) {
        int col = w * 48 + ni * 16 + (l & 15);
        #pragma unroll
        for (int r = 0; r < 4; ++r) {
          int row = mi * 16 + (l >> 4) * 4 + r;
          if (row < nvalid) {
            unsigned e = encf(acc4[mi][ni][r] + b4v[ni]);
            atomicMax(&obuf[(segdL[row] - s_lo) * EE + col], e);
          }
        }
      }
    __syncthreads();
    for (int u = t; u < nloc * EE; u += 512) {
      unsigned e = obuf[u];
      if (e != ENCNI)
        atomicMax(&out_enc[(size_t)(s_lo + u / EE) * EE + (u % EE)], e);
    }
  } else {
    #pragma unroll
    for (int mi = 0; mi < 8; ++mi)
      #pragma unroll
      for (int ni = 0; ni < 3; ++ni) {
        int col = w * 48 + ni * 16 + (l & 15);
        #pragma unroll
        for (int r = 0; r < 4; ++r) {
          int row = mi * 16 + (l >> 4) * 4 + r;
          if (row < nvalid) {
            unsigned e = encf(acc4[mi][ni][r] + b4v[ni]);
            atomicMax(&out_enc[(size_t)segdL[row] * EE + col], e);
          }
        }
      }
  }
}

extern "C" void kernel_launch(void* const* d_in, const int* in_sizes, int n_in,
                              void* d_out, int out_size, void* d_ws, size_t ws_size,
                              hipStream_t stream) {
  (void)in_sizes; (void)n_in; (void)out_size; (void)ws_size;
  const float* x    = (const float*)d_in[0];
  const int*   sidx = (const int*)d_in[1];
  const float* W1   = (const float*)d_in[2];
  const float* b1   = (const float*)d_in[3];
  const float* W2   = (const float*)d_in[4];
  const float* b2   = (const float*)d_in[5];
  const float* W3   = (const float*)d_in[6];
  const float* b3   = (const float*)d_in[7];
  const float* W4   = (const float*)d_in[8];
  const float* b4   = (const float*)d_in[9];
  float* out = (float*)d_out;

  char* ws = (char*)d_ws;
  size_t off = 0;
  auto alloc = [&](size_t bytes) {
    void* p = ws + off;
    off = (off + bytes + 255) & ~(size_t)255;
    return p;
  };
  int*      counts  = (int*)alloc(NSEG * 4);
  int*      cursor  = (int*)alloc(NSEG * 4);
  int*      offs    = (int*)alloc((NSEG + 1) * 4);
  int*      perm    = (int*)alloc((size_t)NPTS * 4);
  float*    W12     = (float*)alloc(H2 * NFEAT * 4);
  float*    b12     = (float*)alloc(H2 * 4);
  float*    W3gT    = (float*)alloc((size_t)H2 * H3 * 4);     // 512 KB
  ushort*   W3hP    = (ushort*)alloc((size_t)131072 * 2);     // 256 KB
  ushort*   W4P     = (ushort*)alloc((size_t)196608 * 2);     // 384 KB
  float*    gmaxG   = (float*)alloc((size_t)NSEG * H2 * 4);   // 2 MB
  float*    gpartG  = (float*)alloc((size_t)NSEG * H3 * 4);   // 4 MB
  unsigned* out_enc = (unsigned*)alloc((size_t)NSEG * EE * 4);// 3 MB

  zero_counts<<<(NSEG + 255) / 256, 256, 0, stream>>>(counts, cursor);
  const int preptotal = 150528 + 24576;
  prep_weights<<<(preptotal + 255) / 256, 256, 0, stream>>>(W1, b1, W2, b2, W3, W4,
                                                            W12, b12, W3gT, W3hP, W4P);
  hist_kernel<<<(NPTS + 255) / 256, 256, 0, stream>>>(sidx, counts);
  scan_kernel<<<1, 1024, 0, stream>>>(counts, offs);
  scatter_kernel<<<(NPTS + 255) / 256, 256, 0, stream>>>(sidx, offs, cursor, perm);
  seg_kernel<<<NSEG, 256, 0, stream>>>(x, perm, offs, W12, b12, gmaxG);
  gpart_kernel<<<NSEG / 64, 256, 0, stream>>>(gmaxG, W3gT, b3, gpartG);
  init_enc_kernel<<<(NSEG * EE + 255) / 256, 256, 0, stream>>>(out_enc);
  main_kernel<<<NPTS / MT, 512, 0, stream>>>(x, perm, sidx, W12, b12,
                                             W3hP, W4P, gpartG, b4, out_enc);
  finalize_kernel<<<(NSEG * EE + 255) / 256, 256, 0, stream>>>(out_enc, out);
}

// Round 6
// 847.384 us; speedup vs baseline: 7.4967x; 1.1708x over previous
//
#include <hip/hip_runtime.h>
#include <hip/hip_bf16.h>
#include <math.h>

#define BB    4
#define NN    100000
#define NFEAT 11
#define NSP   512
#define NSEG  (BB*NSP)     // 2048
#define NPTS  (BB*NN)      // 400000
#define H2    256
#define H3    512
#define EE    384
#define MT    64           // M-tile rows (NPTS % MT == 0)
#define GS    (MT*8)       // granule stride in ushorts (16B per row)
#define MI_N  (MT/16)      // MFMA row-tiles per column of acc
#define MAXL  15           // max distinct segments per tile (fast path)
#define ENCNI 0x007FFFFFu  // enc(-inf)

typedef __attribute__((ext_vector_type(8))) short short8;
typedef __attribute__((ext_vector_type(4))) float f32x4;

__device__ __forceinline__ ushort f2bf(float f) {
  unsigned u = __builtin_bit_cast(unsigned, f);
  unsigned r = (u + 0x7FFFu + ((u >> 16) & 1u)) >> 16;
  return (ushort)r;
}
__device__ __forceinline__ unsigned encf(float f) {
  unsigned u = __builtin_bit_cast(unsigned, f);
  return u ^ ((unsigned)((int)u >> 31) | 0x80000000u);
}
__device__ __forceinline__ float decf(unsigned e) {
  unsigned u = (e & 0x80000000u) ? (e ^ 0x80000000u) : ~e;
  return __builtin_bit_cast(float, u);
}

// ---------------- sort pipeline (validated R1) ----------------
__global__ void zero_counts(int* __restrict__ counts, int* __restrict__ cursor) {
  int i = blockIdx.x * blockDim.x + threadIdx.x;
  if (i < NSEG) { counts[i] = 0; cursor[i] = 0; }
}

__global__ void hist_kernel(const int* __restrict__ sidx, int* __restrict__ counts) {
  int i = blockIdx.x * blockDim.x + threadIdx.x;
  if (i < NPTS) {
    int seg = sidx[i] + (i / NN) * NSP;
    atomicAdd(&counts[seg], 1);
  }
}

__global__ void scan_kernel(const int* __restrict__ counts, int* __restrict__ offs) {
  __shared__ int buf[1024];
  int t = threadIdx.x;
  int c0 = counts[2 * t], c1 = counts[2 * t + 1];
  int s = c0 + c1;
  buf[t] = s;
  __syncthreads();
  for (int d = 1; d < 1024; d <<= 1) {
    int add = (t >= d) ? buf[t - d] : 0;
    __syncthreads();
    buf[t] += add;
    __syncthreads();
  }
  int incl = buf[t];
  int excl = incl - s;
  offs[2 * t] = excl;
  offs[2 * t + 1] = excl + c0;
  if (t == 1023) offs[2048] = incl;
}

__global__ void scatter_kernel(const int* __restrict__ sidx, const int* __restrict__ offs,
                               int* __restrict__ cursor, int* __restrict__ perm) {
  int i = blockIdx.x * blockDim.x + threadIdx.x;
  if (i < NPTS) {
    int seg = sidx[i] + (i / NN) * NSP;
    int pos = offs[seg] + atomicAdd(&cursor[seg], 1);
    perm[pos] = i;
  }
}

// ---------------- weight prep (packing formats validated R2/R3) ----------------
__global__ void prep_weights(const float* __restrict__ W1, const float* __restrict__ b1,
                             const float* __restrict__ W2, const float* __restrict__ b2,
                             const float* __restrict__ W3, const float* __restrict__ W4,
                             float* __restrict__ W12, float* __restrict__ b12,
                             float* __restrict__ W3gT, ushort* __restrict__ W3hP,
                             ushort* __restrict__ W4P) {
  int u = blockIdx.x * blockDim.x + threadIdx.x;
  if (u < H2 * NFEAT) {                           // 2816
    int c = u / NFEAT, f = u - c * NFEAT;
    float acc = 0.f;
    for (int j = 0; j < 128; ++j) acc += W2[c * 128 + j] * W1[j * NFEAT + f];
    W12[u] = acc;
  } else if (u < 3072) {                          // b12
    int c = u - H2 * NFEAT;
    float acc = b2[c];
    for (int j = 0; j < 128; ++j) acc += W2[c * 128 + j] * b1[j];
    b12[c] = acc;
  } else if (u < 3072 + 131072) {                 // W3gT fp32 [c][o]
    int v = u - 3072;
    int c = v >> 9, o = v & 511;
    W3gT[v] = W3[o * H3 + c];
  } else if (u < 134144 + 16384) {                // W3hP
    int v = u - 134144;
    int ks = v >> 11, rem = v & 2047;
    int nt = rem >> 6, l = rem & 63;
    int n = nt * 16 + (l & 15);
    #pragma unroll
    for (int j = 0; j < 8; ++j) {
      int k = ks * 32 + (l >> 4) * 8 + j;
      W3hP[(size_t)v * 8 + j] = f2bf(W3[n * H3 + H2 + k]);
    }
  } else if (u < 150528 + 24576) {                // W4P
    int v = u - 150528;
    int ks = v / 1536, rem = v - ks * 1536;
    int nt = rem >> 6, l = rem & 63;
    int n = nt * 16 + (l & 15);
    #pragma unroll
    for (int j = 0; j < 8; ++j) {
      int k = ks * 32 + (l >> 4) * 8 + j;
      W4P[(size_t)v * 8 + j] = f2bf(W4[n * H3 + k]);
    }
  }
}

// ---------------- per-segment: gmax only (fp32) ----------------
__global__ __launch_bounds__(256) void seg_kernel(
    const float* __restrict__ x, const int* __restrict__ perm,
    const int* __restrict__ offs,
    const float* __restrict__ W12, const float* __restrict__ b12,
    float* __restrict__ gmaxG) {
  __shared__ float W12s[H2 * NFEAT];
  __shared__ float b12s[H2];
  __shared__ float xs[64 * NFEAT];

  const int s = blockIdx.x;
  const int t = threadIdx.x;
  const int beg = offs[s];
  const int cnt = offs[s + 1] - beg;
  if (cnt == 0) return;

  for (int u = t; u < H2 * NFEAT; u += 256) W12s[u] = W12[u];
  b12s[t] = b12[t];
  __syncthreads();

  float gm = -INFINITY;
  for (int base = 0; base < cnt; base += 64) {
    int m = min(64, cnt - base);
    __syncthreads();
    for (int u = t; u < m * NFEAT; u += 256) {
      int p = u / NFEAT, f = u - p * NFEAT;
      xs[u] = x[(size_t)perm[beg + base + p] * NFEAT + f];
    }
    __syncthreads();
    for (int p = 0; p < m; ++p) {
      float acc = b12s[t];
      #pragma unroll
      for (int f = 0; f < NFEAT; ++f) acc += W12s[t * NFEAT + f] * xs[p * NFEAT + f];
      gm = fmaxf(gm, acc);
    }
  }
  gmaxG[(size_t)s * H2 + t] = gm;
}

// ---------------- gpart = b3 + gmax @ W3g^T (fp32, flat) ----------------
__global__ __launch_bounds__(256) void gpart_kernel(
    const float* __restrict__ gmaxG, const float* __restrict__ W3gT,
    const float* __restrict__ b3, float* __restrict__ gpartG) {
  __shared__ float gm[64 * 256];   // 64 KB
  const int t = threadIdx.x;
  const int b = blockIdx.x;        // 32 blocks x 64 segs
  for (int u = t; u < 64 * 256; u += 256) gm[u] = gmaxG[(size_t)b * 64 * 256 + u];
  __syncthreads();
  const float bb0 = b3[t], bb1 = b3[t + 256];
  for (int grp = 0; grp < 4; ++grp) {
    float a0[16], a1[16];
    #pragma unroll
    for (int sg = 0; sg < 16; ++sg) { a0[sg] = bb0; a1[sg] = bb1; }
    for (int c = 0; c < 256; ++c) {
      float w0 = W3gT[c * 512 + t], w1 = W3gT[c * 512 + t + 256];
      #pragma unroll
      for (int sg = 0; sg < 16; ++sg) {
        float gv = gm[(grp * 16 + sg) * 256 + c];
        a0[sg] += w0 * gv; a1[sg] += w1 * gv;
      }
    }
    #pragma unroll
    for (int sg = 0; sg < 16; ++sg) {
      size_t s = (size_t)b * 64 + grp * 16 + sg;
      gpartG[s * 512 + t] = a0[sg];
      gpartG[s * 512 + t + 256] = a1[sg];
    }
  }
}

__global__ void init_enc_kernel(unsigned* __restrict__ enc) {
  int i = blockIdx.x * 256 + threadIdx.x;
  if (i < NSEG * EE) enc[i] = ENCNI;
}

__global__ void finalize_kernel(const unsigned* __restrict__ enc, float* __restrict__ out) {
  int i = blockIdx.x * 256 + threadIdx.x;
  if (i < NSEG * EE) out[i] = decf(enc[i]);
}

// ---------------- main: flat-M fused MFMA, MT=64, 8 waves ----------------
// R6: R5 re-parameterized MT 128->64 (+MAXL 16->15) so LDS = 81.2 KB ->
// 2 blocks/CU: one block's MFMA phases overlap the other's VALU/barrier
// phases. Addressing/logic otherwise identical to validated R5.
__global__ __launch_bounds__(512, 4) void main_kernel(
    const float* __restrict__ x, const int* __restrict__ perm,
    const int* __restrict__ sidx,
    const float* __restrict__ W12, const float* __restrict__ b12,
    const ushort* __restrict__ W3hP, const ushort* __restrict__ W4P,
    const float* __restrict__ gpartG, const float* __restrict__ b4,
    unsigned* __restrict__ out_enc) {
  __shared__ __align__(16) ushort hsE[MT * 256];    // 32 KB  h tile [gran][row]
  __shared__ __align__(16) ushort regB[MT * 256];   // 32 KB  overlay: xs/W12/b12 -> y1 half -> obuf
  __shared__ float gpartL[MAXL * 256];              // 15 KB
  __shared__ int segdL[MT];
  __shared__ int s_loS, nlocS;

  const int t = threadIdx.x;
  const int w = t >> 6;        // wave 0..7
  const int l = t & 63;
  const int mbeg = blockIdx.x * MT;
  const int nvalid = min(MT, NPTS - mbeg);

  float* xsF  = (float*)regB;          // 704 floats
  float* W12s = xsF + 704;             // 2816 floats
  float* b12s = W12s + 2816;           // 256 floats
  ushort* y1E = regB;
  unsigned* obuf = (unsigned*)regB;

  // ---- stage x, folded weights, per-row segment ids ----
  for (int u = t; u < MT * NFEAT; u += 512) {
    int p = u / NFEAT, f = u - p * NFEAT;
    xsF[u] = (p < nvalid) ? x[(size_t)perm[mbeg + p] * NFEAT + f] : 0.f;
  }
  for (int u = t; u < 2816; u += 512) W12s[u] = W12[u];
  if (t < 256) b12s[t] = b12[t];
  if (t < MT) {
    int sg = 0;
    if (t < nvalid) {
      int i = perm[mbeg + t];
      sg = sidx[i] + (i / NN) * NSP;
    }
    segdL[t] = sg;
  }
  __syncthreads();
  if (t == 0) {
    s_loS = segdL[0];
    nlocS = segdL[nvalid - 1] - segdL[0] + 1;
  }
  __syncthreads();
  const int s_lo = s_loS;
  const int nloc = nlocS;
  const bool fb = (nloc > MAXL);    // pathological fallback
  if (t < MT && t >= nvalid) segdL[t] = s_lo;

  // ---- h compute -> hsE[gran][row] : gran wave-uniform, row = rr*64 + lane ----
  #pragma unroll
  for (int i = 0; i < 4; ++i) {
    int gran = i * 8 + w;          // wave-uniform -> W12s reads broadcast
    int cb = gran * 8;
    #pragma unroll
    for (int rr = 0; rr < MT / 64; ++rr) {
      int row = rr * 64 + l;
      uint4 pkt = {0, 0, 0, 0};
      if (row < nvalid) {
        float acc[8];
        #pragma unroll
        for (int cj = 0; cj < 8; ++cj) acc[cj] = b12s[cb + cj];
        #pragma unroll
        for (int f = 0; f < NFEAT; ++f) {
          float xv = xsF[row * NFEAT + f];
          #pragma unroll
          for (int cj = 0; cj < 8; ++cj) acc[cj] += W12s[(cb + cj) * NFEAT + f] * xv;
        }
        pkt.x = (unsigned)f2bf(acc[0]) | ((unsigned)f2bf(acc[1]) << 16);
        pkt.y = (unsigned)f2bf(acc[2]) | ((unsigned)f2bf(acc[3]) << 16);
        pkt.z = (unsigned)f2bf(acc[4]) | ((unsigned)f2bf(acc[5]) << 16);
        pkt.w = (unsigned)f2bf(acc[6]) | ((unsigned)f2bf(acc[7]) << 16);
      }
      *(uint4*)&hsE[gran * GS + row * 8] = pkt;   // contiguous 1KB per wave-step
    }
  }
  __syncthreads();   // hsE ready; xsF (regB overlay) free; segdL fixed

  float b4v[3];
  #pragma unroll
  for (int ni = 0; ni < 3; ++ni) b4v[ni] = b4[w * 48 + ni * 16 + (l & 15)];

  f32x4 acc4[MI_N][3];
  #pragma unroll
  for (int mi = 0; mi < MI_N; ++mi)
    #pragma unroll
    for (int ni = 0; ni < 3; ++ni)
      acc4[mi][ni] = (f32x4){0.f, 0.f, 0.f, 0.f};

  #pragma unroll
  for (int hf = 0; hf < 2; ++hf) {
    // stage this half's gpart rows for the tile's local segments
    if (!fb) {
      for (int u = t; u < nloc * 256; u += 512) {
        int sg = u >> 8, c = u & 255;
        gpartL[u] = gpartG[(size_t)(s_lo + sg) * 512 + hf * 256 + c];
      }
    }

    // ---- layer3 (this half): wave w -> 2 ntiles (32 cols) ----
    f32x4 acc3[MI_N][2];
    #pragma unroll
    for (int mi = 0; mi < MI_N; ++mi)
      #pragma unroll
      for (int ni = 0; ni < 2; ++ni)
        acc3[mi][ni] = (f32x4){0.f, 0.f, 0.f, 0.f};

    #pragma unroll
    for (int ks = 0; ks < 8; ++ks) {
      short8 bfr[2];
      #pragma unroll
      for (int ni = 0; ni < 2; ++ni) {
        int nt = hf * 16 + w * 2 + ni;
        bfr[ni] = *(const short8*)&W3hP[(size_t)((ks * 32 + nt) * 64 + l) * 8];
      }
      #pragma unroll
      for (int mi = 0; mi < MI_N; ++mi) {
        short8 a = *(const short8*)&hsE[(ks * 4 + (l >> 4)) * GS + (mi * 16 + (l & 15)) * 8];
        acc3[mi][0] = __builtin_amdgcn_mfma_f32_16x16x32_bf16(a, bfr[0], acc3[mi][0], 0, 0, 0);
        acc3[mi][1] = __builtin_amdgcn_mfma_f32_16x16x32_bf16(a, bfr[1], acc3[mi][1], 0, 0, 0);
      }
    }
    __syncthreads();   // gpartL staged; previous regB readers done

    // ---- bias(gpart) + relu -> y1E[gran][row] ----
    #pragma unroll
    for (int mi = 0; mi < MI_N; ++mi)
      #pragma unroll
      for (int ni = 0; ni < 2; ++ni) {
        int colh = w * 32 + ni * 16 + (l & 15);
        #pragma unroll
        for (int r = 0; r < 4; ++r) {
          int row = mi * 16 + (l >> 4) * 4 + r;
          int sg = segdL[row];
          float bias = fb ? gpartG[(size_t)sg * 512 + hf * 256 + colh]
                          : gpartL[(sg - s_lo) * 256 + colh];
          float v = fmaxf(acc3[mi][ni][r] + bias, 0.f);
          y1E[(colh >> 3) * GS + row * 8 + (colh & 7)] = f2bf(v);
        }
      }
    __syncthreads();   // y1E half ready

    // ---- layer4 partial-K: wave w -> 3 ntiles (48 cols) ----
    #pragma unroll
    for (int ks = 0; ks < 8; ++ks) {
      short8 bfr[3];
      #pragma unroll
      for (int ni = 0; ni < 3; ++ni) {
        int ksg = hf * 8 + ks;
        bfr[ni] = *(const short8*)&W4P[(size_t)((ksg * 24 + w * 3 + ni) * 64 + l) * 8];
      }
      #pragma unroll
      for (int mi = 0; mi < MI_N; ++mi) {
        short8 a = *(const short8*)&y1E[(ks * 4 + (l >> 4)) * GS + (mi * 16 + (l & 15)) * 8];
        acc4[mi][0] = __builtin_amdgcn_mfma_f32_16x16x32_bf16(a, bfr[0], acc4[mi][0], 0, 0, 0);
        acc4[mi][1] = __builtin_amdgcn_mfma_f32_16x16x32_bf16(a, bfr[1], acc4[mi][1], 0, 0, 0);
        acc4[mi][2] = __builtin_amdgcn_mfma_f32_16x16x32_bf16(a, bfr[2], acc4[mi][2], 0, 0, 0);
      }
    }
    __syncthreads();   // layer4 done reading y1E (before rewrite / obuf reuse)
  }

  // ---- epilogue: segment-max via LDS enc-atomicMax then global ----
  if (!fb) {
    for (int u = t; u < nloc * EE; u += 512) obuf[u] = ENCNI;
    __syncthreads();
    #pragma unroll
    for (int mi = 0; mi < MI_N; ++mi)
      #pragma unroll
      for (int ni = 0; ni < 3; ++ni) {
        int col = w * 48 + ni * 16 + (l & 15);
        #pragma unroll
        for (int r = 0; r < 4; ++r) {
          int row = mi * 16 + (l >> 4) * 4 + r;
          if (row < nvalid) {
            unsigned e = encf(acc4[mi][ni][r] + b4v[ni]);
            atomicMax(&obuf[(segdL[row] - s_lo) * EE + col], e);
          }
        }
      }
    __syncthreads();
    for (int u = t; u < nloc * EE; u += 512) {
      unsigned e = obuf[u];
      if (e != ENCNI)
        atomicMax(&out_enc[(size_t)(s_lo + u / EE) * EE + (u % EE)], e);
    }
  } else {
    #pragma unroll
    for (int mi = 0; mi < MI_N; ++mi)
      #pragma unroll
      for (int ni = 0; ni < 3; ++ni) {
        int col = w * 48 + ni * 16 + (l & 15);
        #pragma unroll
        for (int r = 0; r < 4; ++r) {
          int row = mi * 16 + (l >> 4) * 4 + r;
          if (row < nvalid) {
            unsigned e = encf(acc4[mi][ni][r] + b4v[ni]);
            atomicMax(&out_enc[(size_t)segdL[row] * EE + col], e);
          }
        }
      }
  }
}

extern "C" void kernel_launch(void* const* d_in, const int* in_sizes, int n_in,
                              void* d_out, int out_size, void* d_ws, size_t ws_size,
                              hipStream_t stream) {
  (void)in_sizes; (void)n_in; (void)out_size; (void)ws_size;
  const float* x    = (const float*)d_in[0];
  const int*   sidx = (const int*)d_in[1];
  const float* W1   = (const float*)d_in[2];
  const float* b1   = (const float*)d_in[3];
  const float* W2   = (const float*)d_in[4];
  const float* b2   = (const float*)d_in[5];
  const float* W3   = (const float*)d_in[6];
  const float* b3   = (const float*)d_in[7];
  const float* W4   = (const float*)d_in[8];
  const float* b4   = (const float*)d_in[9];
  float* out = (float*)d_out;

  char* ws = (char*)d_ws;
  size_t off = 0;
  auto alloc = [&](size_t bytes) {
    void* p = ws + off;
    off = (off + bytes + 255) & ~(size_t)255;
    return p;
  };
  int*      counts  = (int*)alloc(NSEG * 4);
  int*      cursor  = (int*)alloc(NSEG * 4);
  int*      offs    = (int*)alloc((NSEG + 1) * 4);
  int*      perm    = (int*)alloc((size_t)NPTS * 4);
  float*    W12     = (float*)alloc(H2 * NFEAT * 4);
  float*    b12     = (float*)alloc(H2 * 4);
  float*    W3gT    = (float*)alloc((size_t)H2 * H3 * 4);     // 512 KB
  ushort*   W3hP    = (ushort*)alloc((size_t)131072 * 2);     // 256 KB
  ushort*   W4P     = (ushort*)alloc((size_t)196608 * 2);     // 384 KB
  float*    gmaxG   = (float*)alloc((size_t)NSEG * H2 * 4);   // 2 MB
  float*    gpartG  = (float*)alloc((size_t)NSEG * H3 * 4);   // 4 MB
  unsigned* out_enc = (unsigned*)alloc((size_t)NSEG * EE * 4);// 3 MB

  zero_counts<<<(NSEG + 255) / 256, 256, 0, stream>>>(counts, cursor);
  const int preptotal = 150528 + 24576;
  prep_weights<<<(preptotal + 255) / 256, 256, 0, stream>>>(W1, b1, W2, b2, W3, W4,
                                                            W12, b12, W3gT, W3hP, W4P);
  hist_kernel<<<(NPTS + 255) / 256, 256, 0, stream>>>(sidx, counts);
  scan_kernel<<<1, 1024, 0, stream>>>(counts, offs);
  scatter_kernel<<<(NPTS + 255) / 256, 256, 0, stream>>>(sidx, offs, cursor, perm);
  seg_kernel<<<NSEG, 256, 0, stream>>>(x, perm, offs, W12, b12, gmaxG);
  gpart_kernel<<<NSEG / 64, 256, 0, stream>>>(gmaxG, W3gT, b3, gpartG);
  init_enc_kernel<<<(NSEG * EE + 255) / 256, 256, 0, stream>>>(out_enc);
  main_kernel<<<NPTS / MT, 512, 0, stream>>>(x, perm, sidx, W12, b12,
                                             W3hP, W4P, gpartG, b4, out_enc);
  finalize_kernel<<<(NSEG * EE + 255) / 256, 256, 0, stream>>>(out_enc, out);
}

// Round 7
// 832.805 us; speedup vs baseline: 7.6279x; 1.0175x over previous
//
#include <hip/hip_runtime.h>
#include <hip/hip_bf16.h>
#include <math.h>

#define BB    4
#define NN    100000
#define NFEAT 11
#define NSP   512
#define NSEG  (BB*NSP)     // 2048
#define NPTS  (BB*NN)      // 400000
#define H2    256
#define H3    512
#define EE    384
#define MT    64           // M-tile rows (NPTS % MT == 0)
#define GS    (MT*8)       // granule stride in ushorts (16B per row)
#define MI_N  (MT/16)      // MFMA row-tiles
#define MAXL  15           // max distinct segments per tile (fast path)
#define ENCNI 0x007FFFFFu  // enc(-inf)

typedef __attribute__((ext_vector_type(8))) short short8;
typedef __attribute__((ext_vector_type(4))) float f32x4;

__device__ __forceinline__ ushort f2bf(float f) {
  unsigned u = __builtin_bit_cast(unsigned, f);
  unsigned r = (u + 0x7FFFu + ((u >> 16) & 1u)) >> 16;
  return (ushort)r;
}
__device__ __forceinline__ unsigned encf(float f) {
  unsigned u = __builtin_bit_cast(unsigned, f);
  return u ^ ((unsigned)((int)u >> 31) | 0x80000000u);
}
__device__ __forceinline__ float decf(unsigned e) {
  unsigned u = (e & 0x80000000u) ? (e ^ 0x80000000u) : ~e;
  return __builtin_bit_cast(float, u);
}

// ---------------- combined init: counts/cursor zero, gmaxEnc/out_enc = enc(-inf) ----
__global__ void init_all(int* __restrict__ counts, int* __restrict__ cursor,
                         unsigned* __restrict__ gmaxEnc, unsigned* __restrict__ out_enc) {
  int i = blockIdx.x * 256 + threadIdx.x;
  if (i < NSEG * EE) out_enc[i] = ENCNI;
  if (i < NSEG * H2) gmaxEnc[i] = ENCNI;
  if (i < NSEG) { counts[i] = 0; cursor[i] = 0; }
}

__global__ void hist_kernel(const int* __restrict__ sidx, int* __restrict__ counts) {
  int i = blockIdx.x * blockDim.x + threadIdx.x;
  if (i < NPTS) {
    int seg = sidx[i] + (i / NN) * NSP;
    atomicAdd(&counts[seg], 1);
  }
}

__global__ void scan_kernel(const int* __restrict__ counts, int* __restrict__ offs) {
  __shared__ int buf[1024];
  int t = threadIdx.x;
  int c0 = counts[2 * t], c1 = counts[2 * t + 1];
  int s = c0 + c1;
  buf[t] = s;
  __syncthreads();
  for (int d = 1; d < 1024; d <<= 1) {
    int add = (t >= d) ? buf[t - d] : 0;
    __syncthreads();
    buf[t] += add;
    __syncthreads();
  }
  int incl = buf[t];
  int excl = incl - s;
  offs[2 * t] = excl;
  offs[2 * t + 1] = excl + c0;
  if (t == 1023) offs[2048] = incl;
}

// scatter: perm[pos] = original index, segp[pos] = global segment id
__global__ void scatter_kernel(const int* __restrict__ sidx, const int* __restrict__ offs,
                               int* __restrict__ cursor, int* __restrict__ perm,
                               int* __restrict__ segp) {
  int i = blockIdx.x * blockDim.x + threadIdx.x;
  if (i < NPTS) {
    int seg = sidx[i] + (i / NN) * NSP;
    int pos = offs[seg] + atomicAdd(&cursor[seg], 1);
    perm[pos] = i;
    segp[pos] = seg;
  }
}

// ---------------- weight prep (packing formats validated R2/R3) ----------------
__global__ void prep_weights(const float* __restrict__ W1, const float* __restrict__ b1,
                             const float* __restrict__ W2, const float* __restrict__ b2,
                             const float* __restrict__ W3, const float* __restrict__ W4,
                             float* __restrict__ W12, float* __restrict__ b12,
                             float* __restrict__ W3gT, ushort* __restrict__ W3hP,
                             ushort* __restrict__ W4P) {
  int u = blockIdx.x * blockDim.x + threadIdx.x;
  if (u < H2 * NFEAT) {                           // 2816
    int c = u / NFEAT, f = u - c * NFEAT;
    float acc = 0.f;
    for (int j = 0; j < 128; ++j) acc += W2[c * 128 + j] * W1[j * NFEAT + f];
    W12[u] = acc;
  } else if (u < 3072) {                          // b12
    int c = u - H2 * NFEAT;
    float acc = b2[c];
    for (int j = 0; j < 128; ++j) acc += W2[c * 128 + j] * b1[j];
    b12[c] = acc;
  } else if (u < 3072 + 131072) {                 // W3gT fp32 [c][o]
    int v = u - 3072;
    int c = v >> 9, o = v & 511;
    W3gT[v] = W3[o * H3 + c];
  } else if (u < 134144 + 16384) {                // W3hP
    int v = u - 134144;
    int ks = v >> 11, rem = v & 2047;
    int nt = rem >> 6, l = rem & 63;
    int n = nt * 16 + (l & 15);
    #pragma unroll
    for (int j = 0; j < 8; ++j) {
      int k = ks * 32 + (l >> 4) * 8 + j;
      W3hP[(size_t)v * 8 + j] = f2bf(W3[n * H3 + H2 + k]);
    }
  } else if (u < 150528 + 24576) {                // W4P
    int v = u - 150528;
    int ks = v / 1536, rem = v - ks * 1536;
    int nt = rem >> 6, l = rem & 63;
    int n = nt * 16 + (l & 15);
    #pragma unroll
    for (int j = 0; j < 8; ++j) {
      int k = ks * 32 + (l >> 4) * 8 + j;
      W4P[(size_t)v * 8 + j] = f2bf(W4[n * H3 + k]);
    }
  }
}

// ---------------- flat gmax: thread = (channel, half-of-64-rows), serial run-max ----
// max is exactly order-independent -> gmax bit-identical to per-segment version.
__global__ __launch_bounds__(512) void seg_flat(
    const float* __restrict__ x, const int* __restrict__ perm,
    const int* __restrict__ segp,
    const float* __restrict__ W12, const float* __restrict__ b12,
    unsigned* __restrict__ gmaxEnc) {
  __shared__ float W12s[H2 * NFEAT];
  __shared__ float b12s[H2];
  __shared__ float xs[64 * NFEAT];
  __shared__ int segd[64];

  const int t = threadIdx.x;
  const int mbeg = blockIdx.x * 64;

  for (int u = t; u < 64 * NFEAT; u += 512) {
    int p = u / NFEAT, f = u - p * NFEAT;
    xs[u] = x[(size_t)perm[mbeg + p] * NFEAT + f];
  }
  for (int u = t; u < H2 * NFEAT; u += 512) W12s[u] = W12[u];
  if (t < H2) b12s[t] = b12[t];
  if (t < 64) segd[t] = segp[mbeg + t];
  __syncthreads();

  const int c = t & 255;          // channel
  const int h0 = (t >> 8) * 32;   // row base (0 or 32)
  float wv[NFEAT];
  #pragma unroll
  for (int f = 0; f < NFEAT; ++f) wv[f] = W12s[c * NFEAT + f];
  const float bb = b12s[c];

  int cur = segd[h0];
  float m = -INFINITY;
  for (int p = h0; p < h0 + 32; ++p) {
    int sg = segd[p];
    if (sg != cur) {
      atomicMax(&gmaxEnc[(size_t)cur * H2 + c], encf(m));
      cur = sg; m = -INFINITY;
    }
    float acc = bb;
    #pragma unroll
    for (int f = 0; f < NFEAT; ++f) acc += wv[f] * xs[p * NFEAT + f];
    m = fmaxf(m, acc);
  }
  atomicMax(&gmaxEnc[(size_t)cur * H2 + c], encf(m));
}

// ---------------- gpart = b3 + gmax @ W3g^T (fp32, flat) ----------------
__global__ __launch_bounds__(256) void gpart_kernel(
    const unsigned* __restrict__ gmaxEnc, const float* __restrict__ W3gT,
    const float* __restrict__ b3, float* __restrict__ gpartG) {
  __shared__ float gm[64 * 256];   // 64 KB
  const int t = threadIdx.x;
  const int b = blockIdx.x;        // 32 blocks x 64 segs
  for (int u = t; u < 64 * 256; u += 256) gm[u] = decf(gmaxEnc[(size_t)b * 64 * 256 + u]);
  __syncthreads();
  const float bb0 = b3[t], bb1 = b3[t + 256];
  for (int grp = 0; grp < 4; ++grp) {
    float a0[16], a1[16];
    #pragma unroll
    for (int sg = 0; sg < 16; ++sg) { a0[sg] = bb0; a1[sg] = bb1; }
    for (int c = 0; c < 256; ++c) {
      float w0 = W3gT[c * 512 + t], w1 = W3gT[c * 512 + t + 256];
      #pragma unroll
      for (int sg = 0; sg < 16; ++sg) {
        float gv = gm[(grp * 16 + sg) * 256 + c];
        a0[sg] += w0 * gv; a1[sg] += w1 * gv;
      }
    }
    #pragma unroll
    for (int sg = 0; sg < 16; ++sg) {
      size_t s = (size_t)b * 64 + grp * 16 + sg;
      gpartG[s * 512 + t] = a0[sg];
      gpartG[s * 512 + t + 256] = a1[sg];
    }
  }
}

__global__ void finalize_kernel(const unsigned* __restrict__ enc, float* __restrict__ out) {
  int i = blockIdx.x * 256 + threadIdx.x;
  if (i < NSEG * EE) out[i] = decf(enc[i]);
}

// ---------------- main: flat-M fused MFMA, MT=64, 8 waves, [gran][row] LDS ----
// R7: identical to validated R6 except (a) segdL from segp (same values),
// (b) depth-2 register prefetch of B-fragments (load reorder only; MFMA
// accumulation order unchanged -> numerics identical).
__global__ __launch_bounds__(512, 4) void main_kernel(
    const float* __restrict__ x, const int* __restrict__ perm,
    const int* __restrict__ segp,
    const float* __restrict__ W12, const float* __restrict__ b12,
    const ushort* __restrict__ W3hP, const ushort* __restrict__ W4P,
    const float* __restrict__ gpartG, const float* __restrict__ b4,
    unsigned* __restrict__ out_enc) {
  __shared__ __align__(16) ushort hsE[MT * 256];    // 32 KB  h tile [gran][row]
  __shared__ __align__(16) ushort regB[MT * 256];   // 32 KB  overlay: xs/W12/b12 -> y1 half -> obuf
  __shared__ float gpartL[MAXL * 256];              // 15 KB
  __shared__ int segdL[MT];
  __shared__ int s_loS, nlocS;

  const int t = threadIdx.x;
  const int w = t >> 6;        // wave 0..7
  const int l = t & 63;
  const int mbeg = blockIdx.x * MT;
  const int nvalid = min(MT, NPTS - mbeg);

  float* xsF  = (float*)regB;          // 704 floats
  float* W12s = xsF + 704;             // 2816 floats
  float* b12s = W12s + 2816;           // 256 floats
  ushort* y1E = regB;
  unsigned* obuf = (unsigned*)regB;

  // ---- stage x, folded weights, per-row segment ids ----
  for (int u = t; u < MT * NFEAT; u += 512) {
    int p = u / NFEAT, f = u - p * NFEAT;
    xsF[u] = (p < nvalid) ? x[(size_t)perm[mbeg + p] * NFEAT + f] : 0.f;
  }
  for (int u = t; u < 2816; u += 512) W12s[u] = W12[u];
  if (t < 256) b12s[t] = b12[t];
  if (t < MT) segdL[t] = (t < nvalid) ? segp[mbeg + t] : 0;
  __syncthreads();
  if (t == 0) {
    s_loS = segdL[0];
    nlocS = segdL[nvalid - 1] - segdL[0] + 1;
  }
  __syncthreads();
  const int s_lo = s_loS;
  const int nloc = nlocS;
  const bool fb = (nloc > MAXL);    // pathological fallback
  if (t < MT && t >= nvalid) segdL[t] = s_lo;

  // ---- h compute -> hsE[gran][row] ----
  #pragma unroll
  for (int i = 0; i < 4; ++i) {
    int gran = i * 8 + w;          // wave-uniform -> W12s reads broadcast
    int cb = gran * 8;
    int row = l;
    uint4 pkt = {0, 0, 0, 0};
    if (row < nvalid) {
      float acc[8];
      #pragma unroll
      for (int cj = 0; cj < 8; ++cj) acc[cj] = b12s[cb + cj];
      #pragma unroll
      for (int f = 0; f < NFEAT; ++f) {
        float xv = xsF[row * NFEAT + f];
        #pragma unroll
        for (int cj = 0; cj < 8; ++cj) acc[cj] += W12s[(cb + cj) * NFEAT + f] * xv;
      }
      pkt.x = (unsigned)f2bf(acc[0]) | ((unsigned)f2bf(acc[1]) << 16);
      pkt.y = (unsigned)f2bf(acc[2]) | ((unsigned)f2bf(acc[3]) << 16);
      pkt.z = (unsigned)f2bf(acc[4]) | ((unsigned)f2bf(acc[5]) << 16);
      pkt.w = (unsigned)f2bf(acc[6]) | ((unsigned)f2bf(acc[7]) << 16);
    }
    *(uint4*)&hsE[gran * GS + row * 8] = pkt;
  }
  __syncthreads();   // hsE ready; regB overlay free; segdL fixed

  float b4v[3];
  #pragma unroll
  for (int ni = 0; ni < 3; ++ni) b4v[ni] = b4[w * 48 + ni * 16 + (l & 15)];

  f32x4 acc4[MI_N][3];
  #pragma unroll
  for (int mi = 0; mi < MI_N; ++mi)
    #pragma unroll
    for (int ni = 0; ni < 3; ++ni)
      acc4[mi][ni] = (f32x4){0.f, 0.f, 0.f, 0.f};

  #pragma unroll
  for (int hf = 0; hf < 2; ++hf) {
    if (!fb) {
      for (int u = t; u < nloc * 256; u += 512) {
        int sg = u >> 8, c = u & 255;
        gpartL[u] = gpartG[(size_t)(s_lo + sg) * 512 + hf * 256 + c];
      }
    }

    // ---- layer3 (this half): depth-2 chunked B prefetch ----
    f32x4 acc3[MI_N][2];
    #pragma unroll
    for (int mi = 0; mi < MI_N; ++mi)
      #pragma unroll
      for (int ni = 0; ni < 2; ++ni)
        acc3[mi][ni] = (f32x4){0.f, 0.f, 0.f, 0.f};

    {
      short8 bcur[2][2], bnxt[2][2];
      #pragma unroll
      for (int c2 = 0; c2 < 2; ++c2)
        #pragma unroll
        for (int ni = 0; ni < 2; ++ni)
          bcur[c2][ni] = *(const short8*)&W3hP[(size_t)(((c2) * 32 + hf * 16 + w * 2 + ni) * 64 + l) * 8];
      #pragma unroll
      for (int kc = 0; kc < 4; ++kc) {
        if (kc < 3) {
          #pragma unroll
          for (int c2 = 0; c2 < 2; ++c2)
            #pragma unroll
            for (int ni = 0; ni < 2; ++ni)
              bnxt[c2][ni] = *(const short8*)&W3hP[(size_t)(((kc * 2 + 2 + c2) * 32 + hf * 16 + w * 2 + ni) * 64 + l) * 8];
        }
        #pragma unroll
        for (int c2 = 0; c2 < 2; ++c2) {
          const int ks = kc * 2 + c2;
          #pragma unroll
          for (int mi = 0; mi < MI_N; ++mi) {
            short8 a = *(const short8*)&hsE[(ks * 4 + (l >> 4)) * GS + (mi * 16 + (l & 15)) * 8];
            acc3[mi][0] = __builtin_amdgcn_mfma_f32_16x16x32_bf16(a, bcur[c2][0], acc3[mi][0], 0, 0, 0);
            acc3[mi][1] = __builtin_amdgcn_mfma_f32_16x16x32_bf16(a, bcur[c2][1], acc3[mi][1], 0, 0, 0);
          }
        }
        if (kc < 3) {
          #pragma unroll
          for (int c2 = 0; c2 < 2; ++c2)
            #pragma unroll
            for (int ni = 0; ni < 2; ++ni)
              bcur[c2][ni] = bnxt[c2][ni];
        }
      }
    }
    __syncthreads();   // gpartL staged; previous regB readers done

    // ---- bias(gpart) + relu -> y1E[gran][row] ----
    #pragma unroll
    for (int mi = 0; mi < MI_N; ++mi)
      #pragma unroll
      for (int ni = 0; ni < 2; ++ni) {
        int colh = w * 32 + ni * 16 + (l & 15);
        #pragma unroll
        for (int r = 0; r < 4; ++r) {
          int row = mi * 16 + (l >> 4) * 4 + r;
          int sg = segdL[row];
          float bias = fb ? gpartG[(size_t)sg * 512 + hf * 256 + colh]
                          : gpartL[(sg - s_lo) * 256 + colh];
          float v = fmaxf(acc3[mi][ni][r] + bias, 0.f);
          y1E[(colh >> 3) * GS + row * 8 + (colh & 7)] = f2bf(v);
        }
      }
    __syncthreads();   // y1E half ready

    // ---- layer4 partial-K: depth-2 chunked B prefetch ----
    {
      short8 bcur[2][3], bnxt[2][3];
      #pragma unroll
      for (int c2 = 0; c2 < 2; ++c2)
        #pragma unroll
        for (int ni = 0; ni < 3; ++ni)
          bcur[c2][ni] = *(const short8*)&W4P[(size_t)(((hf * 8 + c2) * 24 + w * 3 + ni) * 64 + l) * 8];
      #pragma unroll
      for (int kc = 0; kc < 4; ++kc) {
        if (kc < 3) {
          #pragma unroll
          for (int c2 = 0; c2 < 2; ++c2)
            #pragma unroll
            for (int ni = 0; ni < 3; ++ni)
              bnxt[c2][ni] = *(const short8*)&W4P[(size_t)(((hf * 8 + kc * 2 + 2 + c2) * 24 + w * 3 + ni) * 64 + l) * 8];
        }
        #pragma unroll
        for (int c2 = 0; c2 < 2; ++c2) {
          const int ks = kc * 2 + c2;
          #pragma unroll
          for (int mi = 0; mi < MI_N; ++mi) {
            short8 a = *(const short8*)&y1E[(ks * 4 + (l >> 4)) * GS + (mi * 16 + (l & 15)) * 8];
            acc4[mi][0] = __builtin_amdgcn_mfma_f32_16x16x32_bf16(a, bcur[c2][0], acc4[mi][0], 0, 0, 0);
            acc4[mi][1] = __builtin_amdgcn_mfma_f32_16x16x32_bf16(a, bcur[c2][1], acc4[mi][1], 0, 0, 0);
            acc4[mi][2] = __builtin_amdgcn_mfma_f32_16x16x32_bf16(a, bcur[c2][2], acc4[mi][2], 0, 0, 0);
          }
        }
        if (kc < 3) {
          #pragma unroll
          for (int c2 = 0; c2 < 2; ++c2)
            #pragma unroll
            for (int ni = 0; ni < 3; ++ni)
              bcur[c2][ni] = bnxt[c2][ni];
        }
      }
    }
    __syncthreads();   // layer4 done reading y1E
  }

  // ---- epilogue: segment-max via LDS enc-atomicMax then global ----
  if (!fb) {
    for (int u = t; u < nloc * EE; u += 512) obuf[u] = ENCNI;
    __syncthreads();
    #pragma unroll
    for (int mi = 0; mi < MI_N; ++mi)
      #pragma unroll
      for (int ni = 0; ni < 3; ++ni) {
        int col = w * 48 + ni * 16 + (l & 15);
        #pragma unroll
        for (int r = 0; r < 4; ++r) {
          int row = mi * 16 + (l >> 4) * 4 + r;
          if (row < nvalid) {
            unsigned e = encf(acc4[mi][ni][r] + b4v[ni]);
            atomicMax(&obuf[(segdL[row] - s_lo) * EE + col], e);
          }
        }
      }
    __syncthreads();
    for (int u = t; u < nloc * EE; u += 512) {
      unsigned e = obuf[u];
      if (e != ENCNI)
        atomicMax(&out_enc[(size_t)(s_lo + u / EE) * EE + (u % EE)], e);
    }
  } else {
    #pragma unroll
    for (int mi = 0; mi < MI_N; ++mi)
      #pragma unroll
      for (int ni = 0; ni < 3; ++ni) {
        int col = w * 48 + ni * 16 + (l & 15);
        #pragma unroll
        for (int r = 0; r < 4; ++r) {
          int row = mi * 16 + (l >> 4) * 4 + r;
          if (row < nvalid) {
            unsigned e = encf(acc4[mi][ni][r] + b4v[ni]);
            atomicMax(&out_enc[(size_t)segdL[row] * EE + col], e);
          }
        }
      }
  }
}

extern "C" void kernel_launch(void* const* d_in, const int* in_sizes, int n_in,
                              void* d_out, int out_size, void* d_ws, size_t ws_size,
                              hipStream_t stream) {
  (void)in_sizes; (void)n_in; (void)out_size; (void)ws_size;
  const float* x    = (const float*)d_in[0];
  const int*   sidx = (const int*)d_in[1];
  const float* W1   = (const float*)d_in[2];
  const float* b1   = (const float*)d_in[3];
  const float* W2   = (const float*)d_in[4];
  const float* b2   = (const float*)d_in[5];
  const float* W3   = (const float*)d_in[6];
  const float* b3   = (const float*)d_in[7];
  const float* W4   = (const float*)d_in[8];
  const float* b4   = (const float*)d_in[9];
  float* out = (float*)d_out;

  char* ws = (char*)d_ws;
  size_t off = 0;
  auto alloc = [&](size_t bytes) {
    void* p = ws + off;
    off = (off + bytes + 255) & ~(size_t)255;
    return p;
  };
  int*      counts  = (int*)alloc(NSEG * 4);
  int*      cursor  = (int*)alloc(NSEG * 4);
  int*      offs    = (int*)alloc((NSEG + 1) * 4);
  int*      perm    = (int*)alloc((size_t)NPTS * 4);
  int*      segp    = (int*)alloc((size_t)NPTS * 4);
  float*    W12     = (float*)alloc(H2 * NFEAT * 4);
  float*    b12     = (float*)alloc(H2 * 4);
  float*    W3gT    = (float*)alloc((size_t)H2 * H3 * 4);      // 512 KB
  ushort*   W3hP    = (ushort*)alloc((size_t)131072 * 2);      // 256 KB
  ushort*   W4P     = (ushort*)alloc((size_t)196608 * 2);      // 384 KB
  unsigned* gmaxEnc = (unsigned*)alloc((size_t)NSEG * H2 * 4); // 2 MB
  float*    gpartG  = (float*)alloc((size_t)NSEG * H3 * 4);    // 4 MB
  unsigned* out_enc = (unsigned*)alloc((size_t)NSEG * EE * 4); // 3 MB

  init_all<<<(NSEG * EE + 255) / 256, 256, 0, stream>>>(counts, cursor, gmaxEnc, out_enc);
  const int preptotal = 150528 + 24576;
  prep_weights<<<(preptotal + 255) / 256, 256, 0, stream>>>(W1, b1, W2, b2, W3, W4,
                                                            W12, b12, W3gT, W3hP, W4P);
  hist_kernel<<<(NPTS + 255) / 256, 256, 0, stream>>>(sidx, counts);
  scan_kernel<<<1, 1024, 0, stream>>>(counts, offs);
  scatter_kernel<<<(NPTS + 255) / 256, 256, 0, stream>>>(sidx, offs, cursor, perm, segp);
  seg_flat<<<NPTS / 64, 512, 0, stream>>>(x, perm, segp, W12, b12, gmaxEnc);
  gpart_kernel<<<NSEG / 64, 256, 0, stream>>>(gmaxEnc, W3gT, b3, gpartG);
  main_kernel<<<NPTS / MT, 512, 0, stream>>>(x, perm, segp, W12, b12,
                                             W3hP, W4P, gpartG, b4, out_enc);
  finalize_kernel<<<(NSEG * EE + 255) / 256, 256, 0, stream>>>(out_enc, out);
}

// Round 8
// 787.634 us; speedup vs baseline: 8.0654x; 1.0574x over previous
//
#include <hip/hip_runtime.h>
#include <hip/hip_bf16.h>
#include <math.h>

#define BB    4
#define NN    100000
#define NFEAT 11
#define NSP   512
#define NSEG  (BB*NSP)     // 2048
#define NPTS  (BB*NN)      // 400000
#define H2    256
#define H3    512
#define EE    384
#define MT    64           // main M-tile rows
#define GS    (MT*8)       // granule stride in ushorts
#define MI_N  (MT/16)
#define MAXL  15           // main: max distinct segments per tile
#define RSEG  512          // gmax kernel rows per block
#define MAXS  12           // gmax kernel: max distinct segments per block
#define ENCNI 0x007FFFFFu  // enc(-inf)

typedef __attribute__((ext_vector_type(8))) short short8;
typedef __attribute__((ext_vector_type(4))) float f32x4;

__device__ __forceinline__ ushort f2bf(float f) {
  unsigned u = __builtin_bit_cast(unsigned, f);
  unsigned r = (u + 0x7FFFu + ((u >> 16) & 1u)) >> 16;
  return (ushort)r;
}
__device__ __forceinline__ unsigned encf(float f) {
  unsigned u = __builtin_bit_cast(unsigned, f);
  return u ^ ((unsigned)((int)u >> 31) | 0x80000000u);
}
__device__ __forceinline__ float decf(unsigned e) {
  unsigned u = (e & 0x80000000u) ? (e ^ 0x80000000u) : ~e;
  return __builtin_bit_cast(float, u);
}

// ---------------- combined init ----------------
__global__ void init_all(int* __restrict__ counts, int* __restrict__ cursor,
                         unsigned* __restrict__ gmaxEnc, unsigned* __restrict__ out_enc) {
  int i = blockIdx.x * 256 + threadIdx.x;
  if (i < NSEG * EE) out_enc[i] = ENCNI;
  if (i < NSEG * H2) gmaxEnc[i] = ENCNI;
  if (i < NSEG) { counts[i] = 0; cursor[i] = 0; }
}

__global__ void hist_kernel(const int* __restrict__ sidx, int* __restrict__ counts) {
  int i = blockIdx.x * blockDim.x + threadIdx.x;
  if (i < NPTS) {
    int seg = sidx[i] + (i / NN) * NSP;
    atomicAdd(&counts[seg], 1);
  }
}

__global__ void scan_kernel(const int* __restrict__ counts, int* __restrict__ offs) {
  __shared__ int buf[1024];
  int t = threadIdx.x;
  int c0 = counts[2 * t], c1 = counts[2 * t + 1];
  int s = c0 + c1;
  buf[t] = s;
  __syncthreads();
  for (int d = 1; d < 1024; d <<= 1) {
    int add = (t >= d) ? buf[t - d] : 0;
    __syncthreads();
    buf[t] += add;
    __syncthreads();
  }
  int incl = buf[t];
  int excl = incl - s;
  offs[2 * t] = excl;
  offs[2 * t + 1] = excl + c0;
  if (t == 1023) offs[2048] = incl;
}

__global__ void scatter_kernel(const int* __restrict__ sidx, const int* __restrict__ offs,
                               int* __restrict__ cursor, int* __restrict__ perm,
                               int* __restrict__ segp) {
  int i = blockIdx.x * blockDim.x + threadIdx.x;
  if (i < NPTS) {
    int seg = sidx[i] + (i / NN) * NSP;
    int pos = offs[seg] + atomicAdd(&cursor[seg], 1);
    perm[pos] = i;
    segp[pos] = seg;
  }
}

// ---------------- weight prep (validated R2/R3) ----------------
__global__ void prep_weights(const float* __restrict__ W1, const float* __restrict__ b1,
                             const float* __restrict__ W2, const float* __restrict__ b2,
                             const float* __restrict__ W3, const float* __restrict__ W4,
                             float* __restrict__ W12, float* __restrict__ b12,
                             float* __restrict__ W3gT, ushort* __restrict__ W3hP,
                             ushort* __restrict__ W4P) {
  int u = blockIdx.x * blockDim.x + threadIdx.x;
  if (u < H2 * NFEAT) {
    int c = u / NFEAT, f = u - c * NFEAT;
    float acc = 0.f;
    for (int j = 0; j < 128; ++j) acc += W2[c * 128 + j] * W1[j * NFEAT + f];
    W12[u] = acc;
  } else if (u < 3072) {
    int c = u - H2 * NFEAT;
    float acc = b2[c];
    for (int j = 0; j < 128; ++j) acc += W2[c * 128 + j] * b1[j];
    b12[c] = acc;
  } else if (u < 3072 + 131072) {
    int v = u - 3072;
    int c = v >> 9, o = v & 511;
    W3gT[v] = W3[o * H3 + c];
  } else if (u < 134144 + 16384) {
    int v = u - 134144;
    int ks = v >> 11, rem = v & 2047;
    int nt = rem >> 6, l = rem & 63;
    int n = nt * 16 + (l & 15);
    #pragma unroll
    for (int j = 0; j < 8; ++j) {
      int k = ks * 32 + (l >> 4) * 8 + j;
      W3hP[(size_t)v * 8 + j] = f2bf(W3[n * H3 + H2 + k]);
    }
  } else if (u < 150528 + 24576) {
    int v = u - 150528;
    int ks = v / 1536, rem = v - ks * 1536;
    int nt = rem >> 6, l = rem & 63;
    int n = nt * 16 + (l & 15);
    #pragma unroll
    for (int j = 0; j < 8; ++j) {
      int k = ks * 32 + (l >> 4) * 8 + j;
      W4P[(size_t)v * 8 + j] = f2bf(W4[n * H3 + k]);
    }
  }
}

// ---------------- gmax: 512-row blocks, W12 frag hoisted to regs ----------------
// thread = (granule g = t>>4 -> 8 channels, row phase r0 = t&15, rows r0+16k).
// h FMA chain identical to main (b12 then f ascending); max order-independent.
// Runs flushed to LDS enc-atomicMax table; interior segs plain-stored, boundary
// segs (<=2 per block) global-atomicMax'd.
__global__ __launch_bounds__(512) void gmax_kernel(
    const float* __restrict__ x, const int* __restrict__ perm,
    const int* __restrict__ segp,
    const float* __restrict__ W12, const float* __restrict__ b12,
    unsigned* __restrict__ gmaxEnc) {
  __shared__ float xs[RSEG * NFEAT];       // 22528 B
  __shared__ float W12s[H2 * NFEAT];       // 11264 B
  __shared__ float b12s[H2];               // 1024 B
  __shared__ int   segd[RSEG];             // 2048 B
  __shared__ unsigned gmaxL[MAXS * H2];    // 12288 B   (48 KB total)

  const int t = threadIdx.x;
  const int mbeg = blockIdx.x * RSEG;
  const int nvalid = min(RSEG, NPTS - mbeg);

  for (int u = t; u < RSEG * NFEAT; u += 512) {
    int p = u / NFEAT, f = u - p * NFEAT;
    xs[u] = (p < nvalid) ? x[(size_t)perm[mbeg + p] * NFEAT + f] : 0.f;
  }
  for (int u = t; u < H2 * NFEAT; u += 512) W12s[u] = W12[u];
  if (t < H2) b12s[t] = b12[t];
  segd[t] = (t < nvalid) ? segp[mbeg + t] : segp[mbeg + nvalid - 1];
  for (int u = t; u < MAXS * H2; u += 512) gmaxL[u] = ENCNI;
  __syncthreads();

  const int s_lo = segd[0];
  const int s_hi = segd[nvalid - 1];
  const bool fb = (s_hi - s_lo + 1) > MAXS;   // pathological fallback

  const int g  = t >> 4;      // granule 0..31 (8 channels)
  const int r0 = t & 15;      // row phase
  const int cb = g * 8;

  float w12r[8][NFEAT], bbr[8];
  #pragma unroll
  for (int cj = 0; cj < 8; ++cj) {
    bbr[cj] = b12s[cb + cj];
    #pragma unroll
    for (int f = 0; f < NFEAT; ++f) w12r[cj][f] = W12s[(cb + cj) * NFEAT + f];
  }

  float m[8];
  #pragma unroll
  for (int cj = 0; cj < 8; ++cj) m[cj] = -INFINITY;
  int cur = segd[r0];
  bool any = false;

  for (int k = 0; k < 32; ++k) {
    int row = r0 + k * 16;
    if (row >= nvalid) break;
    int sg = segd[row];
    if (sg != cur) {
      #pragma unroll
      for (int cj = 0; cj < 8; ++cj) {
        unsigned e = encf(m[cj]);
        if (fb) atomicMax(&gmaxEnc[(size_t)cur * H2 + cb + cj], e);
        else    atomicMax(&gmaxL[(cur - s_lo) * H2 + cb + cj], e);
      }
      cur = sg;
      #pragma unroll
      for (int cj = 0; cj < 8; ++cj) m[cj] = -INFINITY;
    }
    float acc[8];
    #pragma unroll
    for (int cj = 0; cj < 8; ++cj) acc[cj] = bbr[cj];
    #pragma unroll
    for (int f = 0; f < NFEAT; ++f) {
      float xv = xs[row * NFEAT + f];
      #pragma unroll
      for (int cj = 0; cj < 8; ++cj) acc[cj] += w12r[cj][f] * xv;
    }
    #pragma unroll
    for (int cj = 0; cj < 8; ++cj) m[cj] = fmaxf(m[cj], acc[cj]);
    any = true;
  }
  if (any) {
    #pragma unroll
    for (int cj = 0; cj < 8; ++cj) {
      unsigned e = encf(m[cj]);
      if (fb) atomicMax(&gmaxEnc[(size_t)cur * H2 + cb + cj], e);
      else    atomicMax(&gmaxL[(cur - s_lo) * H2 + cb + cj], e);
    }
  }

  __syncthreads();
  if (!fb) {
    int nloc = s_hi - s_lo + 1;
    for (int u = t; u < nloc * H2; u += 512) {
      int sg = s_lo + (u >> 8);
      unsigned v = gmaxL[u];
      if (sg > s_lo && sg < s_hi) gmaxEnc[(size_t)sg * H2 + (u & 255)] = v;   // interior: single writer
      else atomicMax(&gmaxEnc[(size_t)sg * H2 + (u & 255)], v);               // boundary
    }
  }
}

// ---------------- gpart = b3 + gmax @ W3g^T : 256 blocks x 8 segs ----------------
__global__ __launch_bounds__(256) void gpart_kernel(
    const unsigned* __restrict__ gmaxEnc, const float* __restrict__ W3gT,
    const float* __restrict__ b3, float* __restrict__ gpartG) {
  __shared__ float gm[8 * 256];   // 8 KB
  const int t = threadIdx.x;
  const int b = blockIdx.x;       // 256 blocks x 8 segs
  for (int u = t; u < 8 * 256; u += 256) gm[u] = decf(gmaxEnc[(size_t)b * 8 * 256 + u]);
  __syncthreads();
  const float bb0 = b3[t], bb1 = b3[t + 256];
  float a0[8], a1[8];
  #pragma unroll
  for (int sg = 0; sg < 8; ++sg) { a0[sg] = bb0; a1[sg] = bb1; }
  for (int c = 0; c < 256; ++c) {
    float w0 = W3gT[c * 512 + t], w1 = W3gT[c * 512 + t + 256];
    #pragma unroll
    for (int sg = 0; sg < 8; ++sg) {
      float gv = gm[sg * 256 + c];
      a0[sg] += w0 * gv; a1[sg] += w1 * gv;
    }
  }
  #pragma unroll
  for (int sg = 0; sg < 8; ++sg) {
    size_t s = (size_t)b * 8 + sg;
    gpartG[s * 512 + t] = a0[sg];
    gpartG[s * 512 + t + 256] = a1[sg];
  }
}

__global__ void finalize_kernel(const unsigned* __restrict__ enc, float* __restrict__ out) {
  int i = blockIdx.x * 256 + threadIdx.x;
  if (i < NSEG * EE) out[i] = decf(enc[i]);
}

// ---------------- main: unchanged from validated R7 ----------------
__global__ __launch_bounds__(512, 4) void main_kernel(
    const float* __restrict__ x, const int* __restrict__ perm,
    const int* __restrict__ segp,
    const float* __restrict__ W12, const float* __restrict__ b12,
    const ushort* __restrict__ W3hP, const ushort* __restrict__ W4P,
    const float* __restrict__ gpartG, const float* __restrict__ b4,
    unsigned* __restrict__ out_enc) {
  __shared__ __align__(16) ushort hsE[MT * 256];
  __shared__ __align__(16) ushort regB[MT * 256];
  __shared__ float gpartL[MAXL * 256];
  __shared__ int segdL[MT];
  __shared__ int s_loS, nlocS;

  const int t = threadIdx.x;
  const int w = t >> 6;
  const int l = t & 63;
  const int mbeg = blockIdx.x * MT;
  const int nvalid = min(MT, NPTS - mbeg);

  float* xsF  = (float*)regB;
  float* W12s = xsF + 704;
  float* b12s = W12s + 2816;
  ushort* y1E = regB;
  unsigned* obuf = (unsigned*)regB;

  for (int u = t; u < MT * NFEAT; u += 512) {
    int p = u / NFEAT, f = u - p * NFEAT;
    xsF[u] = (p < nvalid) ? x[(size_t)perm[mbeg + p] * NFEAT + f] : 0.f;
  }
  for (int u = t; u < 2816; u += 512) W12s[u] = W12[u];
  if (t < 256) b12s[t] = b12[t];
  if (t < MT) segdL[t] = (t < nvalid) ? segp[mbeg + t] : 0;
  __syncthreads();
  if (t == 0) {
    s_loS = segdL[0];
    nlocS = segdL[nvalid - 1] - segdL[0] + 1;
  }
  __syncthreads();
  const int s_lo = s_loS;
  const int nloc = nlocS;
  const bool fb = (nloc > MAXL);
  if (t < MT && t >= nvalid) segdL[t] = s_lo;

  #pragma unroll
  for (int i = 0; i < 4; ++i) {
    int gran = i * 8 + w;
    int cb = gran * 8;
    int row = l;
    uint4 pkt = {0, 0, 0, 0};
    if (row < nvalid) {
      float acc[8];
      #pragma unroll
      for (int cj = 0; cj < 8; ++cj) acc[cj] = b12s[cb + cj];
      #pragma unroll
      for (int f = 0; f < NFEAT; ++f) {
        float xv = xsF[row * NFEAT + f];
        #pragma unroll
        for (int cj = 0; cj < 8; ++cj) acc[cj] += W12s[(cb + cj) * NFEAT + f] * xv;
      }
      pkt.x = (unsigned)f2bf(acc[0]) | ((unsigned)f2bf(acc[1]) << 16);
      pkt.y = (unsigned)f2bf(acc[2]) | ((unsigned)f2bf(acc[3]) << 16);
      pkt.z = (unsigned)f2bf(acc[4]) | ((unsigned)f2bf(acc[5]) << 16);
      pkt.w = (unsigned)f2bf(acc[6]) | ((unsigned)f2bf(acc[7]) << 16);
    }
    *(uint4*)&hsE[gran * GS + row * 8] = pkt;
  }
  __syncthreads();

  float b4v[3];
  #pragma unroll
  for (int ni = 0; ni < 3; ++ni) b4v[ni] = b4[w * 48 + ni * 16 + (l & 15)];

  f32x4 acc4[MI_N][3];
  #pragma unroll
  for (int mi = 0; mi < MI_N; ++mi)
    #pragma unroll
    for (int ni = 0; ni < 3; ++ni)
      acc4[mi][ni] = (f32x4){0.f, 0.f, 0.f, 0.f};

  #pragma unroll
  for (int hf = 0; hf < 2; ++hf) {
    if (!fb) {
      for (int u = t; u < nloc * 256; u += 512) {
        int sg = u >> 8, c = u & 255;
        gpartL[u] = gpartG[(size_t)(s_lo + sg) * 512 + hf * 256 + c];
      }
    }

    f32x4 acc3[MI_N][2];
    #pragma unroll
    for (int mi = 0; mi < MI_N; ++mi)
      #pragma unroll
      for (int ni = 0; ni < 2; ++ni)
        acc3[mi][ni] = (f32x4){0.f, 0.f, 0.f, 0.f};

    {
      short8 bcur[2][2], bnxt[2][2];
      #pragma unroll
      for (int c2 = 0; c2 < 2; ++c2)
        #pragma unroll
        for (int ni = 0; ni < 2; ++ni)
          bcur[c2][ni] = *(const short8*)&W3hP[(size_t)(((c2) * 32 + hf * 16 + w * 2 + ni) * 64 + l) * 8];
      #pragma unroll
      for (int kc = 0; kc < 4; ++kc) {
        if (kc < 3) {
          #pragma unroll
          for (int c2 = 0; c2 < 2; ++c2)
            #pragma unroll
            for (int ni = 0; ni < 2; ++ni)
              bnxt[c2][ni] = *(const short8*)&W3hP[(size_t)(((kc * 2 + 2 + c2) * 32 + hf * 16 + w * 2 + ni) * 64 + l) * 8];
        }
        #pragma unroll
        for (int c2 = 0; c2 < 2; ++c2) {
          const int ks = kc * 2 + c2;
          #pragma unroll
          for (int mi = 0; mi < MI_N; ++mi) {
            short8 a = *(const short8*)&hsE[(ks * 4 + (l >> 4)) * GS + (mi * 16 + (l & 15)) * 8];
            acc3[mi][0] = __builtin_amdgcn_mfma_f32_16x16x32_bf16(a, bcur[c2][0], acc3[mi][0], 0, 0, 0);
            acc3[mi][1] = __builtin_amdgcn_mfma_f32_16x16x32_bf16(a, bcur[c2][1], acc3[mi][1], 0, 0, 0);
          }
        }
        if (kc < 3) {
          #pragma unroll
          for (int c2 = 0; c2 < 2; ++c2)
            #pragma unroll
            for (int ni = 0; ni < 2; ++ni)
              bcur[c2][ni] = bnxt[c2][ni];
        }
      }
    }
    __syncthreads();

    #pragma unroll
    for (int mi = 0; mi < MI_N; ++mi)
      #pragma unroll
      for (int ni = 0; ni < 2; ++ni) {
        int colh = w * 32 + ni * 16 + (l & 15);
        #pragma unroll
        for (int r = 0; r < 4; ++r) {
          int row = mi * 16 + (l >> 4) * 4 + r;
          int sg = segdL[row];
          float bias = fb ? gpartG[(size_t)sg * 512 + hf * 256 + colh]
                          : gpartL[(sg - s_lo) * 256 + colh];
          float v = fmaxf(acc3[mi][ni][r] + bias, 0.f);
          y1E[(colh >> 3) * GS + row * 8 + (colh & 7)] = f2bf(v);
        }
      }
    __syncthreads();

    {
      short8 bcur[2][3], bnxt[2][3];
      #pragma unroll
      for (int c2 = 0; c2 < 2; ++c2)
        #pragma unroll
        for (int ni = 0; ni < 3; ++ni)
          bcur[c2][ni] = *(const short8*)&W4P[(size_t)(((hf * 8 + c2) * 24 + w * 3 + ni) * 64 + l) * 8];
      #pragma unroll
      for (int kc = 0; kc < 4; ++kc) {
        if (kc < 3) {
          #pragma unroll
          for (int c2 = 0; c2 < 2; ++c2)
            #pragma unroll
            for (int ni = 0; ni < 3; ++ni)
              bnxt[c2][ni] = *(const short8*)&W4P[(size_t)(((hf * 8 + kc * 2 + 2 + c2) * 24 + w * 3 + ni) * 64 + l) * 8];
        }
        #pragma unroll
        for (int c2 = 0; c2 < 2; ++c2) {
          const int ks = kc * 2 + c2;
          #pragma unroll
          for (int mi = 0; mi < MI_N; ++mi) {
            short8 a = *(const short8*)&y1E[(ks * 4 + (l >> 4)) * GS + (mi * 16 + (l & 15)) * 8];
            acc4[mi][0] = __builtin_amdgcn_mfma_f32_16x16x32_bf16(a, bcur[c2][0], acc4[mi][0], 0, 0, 0);
            acc4[mi][1] = __builtin_amdgcn_mfma_f32_16x16x32_bf16(a, bcur[c2][1], acc4[mi][1], 0, 0, 0);
            acc4[mi][2] = __builtin_amdgcn_mfma_f32_16x16x32_bf16(a, bcur[c2][2], acc4[mi][2], 0, 0, 0);
          }
        }
        if (kc < 3) {
          #pragma unroll
          for (int c2 = 0; c2 < 2; ++c2)
            #pragma unroll
            for (int ni = 0; ni < 3; ++ni)
              bcur[c2][ni] = bnxt[c2][ni];
        }
      }
    }
    __syncthreads();
  }

  if (!fb) {
    for (int u = t; u < nloc * EE; u += 512) obuf[u] = ENCNI;
    __syncthreads();
    #pragma unroll
    for (int mi = 0; mi < MI_N; ++mi)
      #pragma unroll
      for (int ni = 0; ni < 3; ++ni) {
        int col = w * 48 + ni * 16 + (l & 15);
        #pragma unroll
        for (int r = 0; r < 4; ++r) {
          int row = mi * 16 + (l >> 4) * 4 + r;
          if (row < nvalid) {
            unsigned e = encf(acc4[mi][ni][r] + b4v[ni]);
            atomicMax(&obuf[(segdL[row] - s_lo) * EE + col], e);
          }
        }
      }
    __syncthreads();
    for (int u = t; u < nloc * EE; u += 512) {
      unsigned e = obuf[u];
      if (e != ENCNI)
        atomicMax(&out_enc[(size_t)(s_lo + u / EE) * EE + (u % EE)], e);
    }
  } else {
    #pragma unroll
    for (int mi = 0; mi < MI_N; ++mi)
      #pragma unroll
      for (int ni = 0; ni < 3; ++ni) {
        int col = w * 48 + ni * 16 + (l & 15);
        #pragma unroll
        for (int r = 0; r < 4; ++r) {
          int row = mi * 16 + (l >> 4) * 4 + r;
          if (row < nvalid) {
            unsigned e = encf(acc4[mi][ni][r] + b4v[ni]);
            atomicMax(&out_enc[(size_t)segdL[row] * EE + col], e);
          }
        }
      }
  }
}

extern "C" void kernel_launch(void* const* d_in, const int* in_sizes, int n_in,
                              void* d_out, int out_size, void* d_ws, size_t ws_size,
                              hipStream_t stream) {
  (void)in_sizes; (void)n_in; (void)out_size; (void)ws_size;
  const float* x    = (const float*)d_in[0];
  const int*   sidx = (const int*)d_in[1];
  const float* W1   = (const float*)d_in[2];
  const float* b1   = (const float*)d_in[3];
  const float* W2   = (const float*)d_in[4];
  const float* b2   = (const float*)d_in[5];
  const float* W3   = (const float*)d_in[6];
  const float* b3   = (const float*)d_in[7];
  const float* W4   = (const float*)d_in[8];
  const float* b4   = (const float*)d_in[9];
  float* out = (float*)d_out;

  char* ws = (char*)d_ws;
  size_t off = 0;
  auto alloc = [&](size_t bytes) {
    void* p = ws + off;
    off = (off + bytes + 255) & ~(size_t)255;
    return p;
  };
  int*      counts  = (int*)alloc(NSEG * 4);
  int*      cursor  = (int*)alloc(NSEG * 4);
  int*      offs    = (int*)alloc((NSEG + 1) * 4);
  int*      perm    = (int*)alloc((size_t)NPTS * 4);
  int*      segp    = (int*)alloc((size_t)NPTS * 4);
  float*    W12     = (float*)alloc(H2 * NFEAT * 4);
  float*    b12     = (float*)alloc(H2 * 4);
  float*    W3gT    = (float*)alloc((size_t)H2 * H3 * 4);
  ushort*   W3hP    = (ushort*)alloc((size_t)131072 * 2);
  ushort*   W4P     = (ushort*)alloc((size_t)196608 * 2);
  unsigned* gmaxEnc = (unsigned*)alloc((size_t)NSEG * H2 * 4);
  float*    gpartG  = (float*)alloc((size_t)NSEG * H3 * 4);
  unsigned* out_enc = (unsigned*)alloc((size_t)NSEG * EE * 4);

  init_all<<<(NSEG * EE + 255) / 256, 256, 0, stream>>>(counts, cursor, gmaxEnc, out_enc);
  const int preptotal = 150528 + 24576;
  prep_weights<<<(preptotal + 255) / 256, 256, 0, stream>>>(W1, b1, W2, b2, W3, W4,
                                                            W12, b12, W3gT, W3hP, W4P);
  hist_kernel<<<(NPTS + 255) / 256, 256, 0, stream>>>(sidx, counts);
  scan_kernel<<<1, 1024, 0, stream>>>(counts, offs);
  scatter_kernel<<<(NPTS + 255) / 256, 256, 0, stream>>>(sidx, offs, cursor, perm, segp);
  gmax_kernel<<<(NPTS + RSEG - 1) / RSEG, 512, 0, stream>>>(x, perm, segp, W12, b12, gmaxEnc);
  gpart_kernel<<<NSEG / 8, 256, 0, stream>>>(gmaxEnc, W3gT, b3, gpartG);
  main_kernel<<<NPTS / MT, 512, 0, stream>>>(x, perm, segp, W12, b12,
                                             W3hP, W4P, gpartG, b4, out_enc);
  finalize_kernel<<<(NSEG * EE + 255) / 256, 256, 0, stream>>>(out_enc, out);
}

// Round 9
// 650.750 us; speedup vs baseline: 9.7620x; 1.2103x over previous
//
#include <hip/hip_runtime.h>
#include <hip/hip_bf16.h>
#include <math.h>

#define BB    4
#define NN    100000
#define NFEAT 11
#define NSP   512
#define NSEG  (BB*NSP)     // 2048
#define NPTS  (BB*NN)      // 400000
#define H2    256
#define H3    512
#define EE    384
#define MT    64           // main M-tile rows (NPTS % MT == 0)
#define GS    (MT*8)       // granule stride in ushorts
#define MI_N  (MT/16)
#define MAXL  15           // main: max distinct segments per tile
#define RSEG  512          // gmax kernel rows per block
#define MAXS  12           // gmax kernel: max distinct segments per block
#define ENCNI 0x007FFFFFu  // enc(-inf)

typedef __attribute__((ext_vector_type(8))) short short8;
typedef __attribute__((ext_vector_type(4))) float f32x4;

__device__ __forceinline__ ushort f2bf(float f) {
  unsigned u = __builtin_bit_cast(unsigned, f);
  unsigned r = (u + 0x7FFFu + ((u >> 16) & 1u)) >> 16;
  return (ushort)r;
}
__device__ __forceinline__ unsigned encf(float f) {
  unsigned u = __builtin_bit_cast(unsigned, f);
  return u ^ ((unsigned)((int)u >> 31) | 0x80000000u);
}
__device__ __forceinline__ float decf(unsigned e) {
  unsigned u = (e & 0x80000000u) ? (e ^ 0x80000000u) : ~e;
  return __builtin_bit_cast(float, u);
}

// ---------------- combined init ----------------
__global__ void init_all(int* __restrict__ counts, int* __restrict__ cursor,
                         unsigned* __restrict__ gmaxEnc, unsigned* __restrict__ out_enc) {
  int i = blockIdx.x * 256 + threadIdx.x;
  if (i < NSEG * EE) out_enc[i] = ENCNI;
  if (i < NSEG * H2) gmaxEnc[i] = ENCNI;
  if (i < NSEG) { counts[i] = 0; cursor[i] = 0; }
}

__global__ void hist_kernel(const int* __restrict__ sidx, int* __restrict__ counts) {
  int i = blockIdx.x * blockDim.x + threadIdx.x;
  if (i < NPTS) {
    int seg = sidx[i] + (i / NN) * NSP;
    atomicAdd(&counts[seg], 1);
  }
}

__global__ void scan_kernel(const int* __restrict__ counts, int* __restrict__ offs) {
  __shared__ int buf[1024];
  int t = threadIdx.x;
  int c0 = counts[2 * t], c1 = counts[2 * t + 1];
  int s = c0 + c1;
  buf[t] = s;
  __syncthreads();
  for (int d = 1; d < 1024; d <<= 1) {
    int add = (t >= d) ? buf[t - d] : 0;
    __syncthreads();
    buf[t] += add;
    __syncthreads();
  }
  int incl = buf[t];
  int excl = incl - s;
  offs[2 * t] = excl;
  offs[2 * t + 1] = excl + c0;
  if (t == 1023) offs[2048] = incl;
}

__global__ void scatter_kernel(const int* __restrict__ sidx, const int* __restrict__ offs,
                               int* __restrict__ cursor, int* __restrict__ perm,
                               int* __restrict__ segp) {
  int i = blockIdx.x * blockDim.x + threadIdx.x;
  if (i < NPTS) {
    int seg = sidx[i] + (i / NN) * NSP;
    int pos = offs[seg] + atomicAdd(&cursor[seg], 1);
    perm[pos] = i;
    segp[pos] = seg;
  }
}

// ---------------- weight prep (validated R2/R3) ----------------
__global__ void prep_weights(const float* __restrict__ W1, const float* __restrict__ b1,
                             const float* __restrict__ W2, const float* __restrict__ b2,
                             const float* __restrict__ W3, const float* __restrict__ W4,
                             float* __restrict__ W12, float* __restrict__ b12,
                             float* __restrict__ W3gT, ushort* __restrict__ W3hP,
                             ushort* __restrict__ W4P) {
  int u = blockIdx.x * blockDim.x + threadIdx.x;
  if (u < H2 * NFEAT) {
    int c = u / NFEAT, f = u - c * NFEAT;
    float acc = 0.f;
    for (int j = 0; j < 128; ++j) acc += W2[c * 128 + j] * W1[j * NFEAT + f];
    W12[u] = acc;
  } else if (u < 3072) {
    int c = u - H2 * NFEAT;
    float acc = b2[c];
    for (int j = 0; j < 128; ++j) acc += W2[c * 128 + j] * b1[j];
    b12[c] = acc;
  } else if (u < 3072 + 131072) {
    int v = u - 3072;
    int c = v >> 9, o = v & 511;
    W3gT[v] = W3[o * H3 + c];
  } else if (u < 134144 + 16384) {
    int v = u - 134144;
    int ks = v >> 11, rem = v & 2047;
    int nt = rem >> 6, l = rem & 63;
    int n = nt * 16 + (l & 15);
    #pragma unroll
    for (int j = 0; j < 8; ++j) {
      int k = ks * 32 + (l >> 4) * 8 + j;
      W3hP[(size_t)v * 8 + j] = f2bf(W3[n * H3 + H2 + k]);
    }
  } else if (u < 150528 + 24576) {
    int v = u - 150528;
    int ks = v / 1536, rem = v - ks * 1536;
    int nt = rem >> 6, l = rem & 63;
    int n = nt * 16 + (l & 15);
    #pragma unroll
    for (int j = 0; j < 8; ++j) {
      int k = ks * 32 + (l >> 4) * 8 + j;
      W4P[(size_t)v * 8 + j] = f2bf(W4[n * H3 + k]);
    }
  }
}

// ---------------- gmax (+optional h store), validated R8 structure ----------------
// thread = (granule g = t>>4 -> 8 channels, row phase r0 = t&15, rows r0+16k).
// h FMA chain identical to main's; f2bf same -> hG bit-identical to main's hsE.
template <bool STOREH>
__global__ __launch_bounds__(512) void gmax_kernel(
    const float* __restrict__ x, const int* __restrict__ perm,
    const int* __restrict__ segp,
    const float* __restrict__ W12, const float* __restrict__ b12,
    unsigned* __restrict__ gmaxEnc, ushort* __restrict__ hG) {
  __shared__ float xs[RSEG * NFEAT];
  __shared__ float W12s[H2 * NFEAT];
  __shared__ float b12s[H2];
  __shared__ int   segd[RSEG];
  __shared__ unsigned gmaxL[MAXS * H2];

  const int t = threadIdx.x;
  const int mbeg = blockIdx.x * RSEG;
  const int nvalid = min(RSEG, NPTS - mbeg);

  for (int u = t; u < RSEG * NFEAT; u += 512) {
    int p = u / NFEAT, f = u - p * NFEAT;
    xs[u] = (p < nvalid) ? x[(size_t)perm[mbeg + p] * NFEAT + f] : 0.f;
  }
  for (int u = t; u < H2 * NFEAT; u += 512) W12s[u] = W12[u];
  if (t < H2) b12s[t] = b12[t];
  segd[t] = (t < nvalid) ? segp[mbeg + t] : segp[mbeg + nvalid - 1];
  for (int u = t; u < MAXS * H2; u += 512) gmaxL[u] = ENCNI;
  __syncthreads();

  const int s_lo = segd[0];
  const int s_hi = segd[nvalid - 1];
  const bool fb = (s_hi - s_lo + 1) > MAXS;

  const int g  = t >> 4;
  const int r0 = t & 15;
  const int cb = g * 8;

  float w12r[8][NFEAT], bbr[8];
  #pragma unroll
  for (int cj = 0; cj < 8; ++cj) {
    bbr[cj] = b12s[cb + cj];
    #pragma unroll
    for (int f = 0; f < NFEAT; ++f) w12r[cj][f] = W12s[(cb + cj) * NFEAT + f];
  }

  float m[8];
  #pragma unroll
  for (int cj = 0; cj < 8; ++cj) m[cj] = -INFINITY;
  int cur = segd[r0];
  bool any = false;

  for (int k = 0; k < 32; ++k) {
    int row = r0 + k * 16;
    if (row >= nvalid) break;
    int sg = segd[row];
    if (sg != cur) {
      #pragma unroll
      for (int cj = 0; cj < 8; ++cj) {
        unsigned e = encf(m[cj]);
        if (fb) atomicMax(&gmaxEnc[(size_t)cur * H2 + cb + cj], e);
        else    atomicMax(&gmaxL[(cur - s_lo) * H2 + cb + cj], e);
      }
      cur = sg;
      #pragma unroll
      for (int cj = 0; cj < 8; ++cj) m[cj] = -INFINITY;
    }
    float acc[8];
    #pragma unroll
    for (int cj = 0; cj < 8; ++cj) acc[cj] = bbr[cj];
    #pragma unroll
    for (int f = 0; f < NFEAT; ++f) {
      float xv = xs[row * NFEAT + f];
      #pragma unroll
      for (int cj = 0; cj < 8; ++cj) acc[cj] += w12r[cj][f] * xv;
    }
    if (STOREH) {
      uint4 pkt;
      pkt.x = (unsigned)f2bf(acc[0]) | ((unsigned)f2bf(acc[1]) << 16);
      pkt.y = (unsigned)f2bf(acc[2]) | ((unsigned)f2bf(acc[3]) << 16);
      pkt.z = (unsigned)f2bf(acc[4]) | ((unsigned)f2bf(acc[5]) << 16);
      pkt.w = (unsigned)f2bf(acc[6]) | ((unsigned)f2bf(acc[7]) << 16);
      int pt = mbeg + row;
      *(uint4*)&hG[(size_t)(pt >> 6) * 16384 + ((size_t)g * 64 + (pt & 63)) * 8] = pkt;
    }
    #pragma unroll
    for (int cj = 0; cj < 8; ++cj) m[cj] = fmaxf(m[cj], acc[cj]);
    any = true;
  }
  if (any) {
    #pragma unroll
    for (int cj = 0; cj < 8; ++cj) {
      unsigned e = encf(m[cj]);
      if (fb) atomicMax(&gmaxEnc[(size_t)cur * H2 + cb + cj], e);
      else    atomicMax(&gmaxL[(cur - s_lo) * H2 + cb + cj], e);
    }
  }

  __syncthreads();
  if (!fb) {
    int nloc = s_hi - s_lo + 1;
    for (int u = t; u < nloc * H2; u += 512) {
      int sg = s_lo + (u >> 8);
      unsigned v = gmaxL[u];
      if (sg > s_lo && sg < s_hi) gmaxEnc[(size_t)sg * H2 + (u & 255)] = v;
      else atomicMax(&gmaxEnc[(size_t)sg * H2 + (u & 255)], v);
    }
  }
}

// ---------------- gpart = b3 + gmax @ W3g^T : 256 blocks x 8 segs ----------------
__global__ __launch_bounds__(256) void gpart_kernel(
    const unsigned* __restrict__ gmaxEnc, const float* __restrict__ W3gT,
    const float* __restrict__ b3, float* __restrict__ gpartG) {
  __shared__ float gm[8 * 256];
  const int t = threadIdx.x;
  const int b = blockIdx.x;
  for (int u = t; u < 8 * 256; u += 256) gm[u] = decf(gmaxEnc[(size_t)b * 8 * 256 + u]);
  __syncthreads();
  const float bb0 = b3[t], bb1 = b3[t + 256];
  float a0[8], a1[8];
  #pragma unroll
  for (int sg = 0; sg < 8; ++sg) { a0[sg] = bb0; a1[sg] = bb1; }
  for (int c = 0; c < 256; ++c) {
    float w0 = W3gT[c * 512 + t], w1 = W3gT[c * 512 + t + 256];
    #pragma unroll
    for (int sg = 0; sg < 8; ++sg) {
      float gv = gm[sg * 256 + c];
      a0[sg] += w0 * gv; a1[sg] += w1 * gv;
    }
  }
  #pragma unroll
  for (int sg = 0; sg < 8; ++sg) {
    size_t s = (size_t)b * 8 + sg;
    gpartG[s * 512 + t] = a0[sg];
    gpartG[s * 512 + t + 256] = a1[sg];
  }
}

__global__ void finalize_kernel(const unsigned* __restrict__ enc, float* __restrict__ out) {
  int i = blockIdx.x * 256 + threadIdx.x;
  if (i < NSEG * EE) out[i] = decf(enc[i]);
}

// ---------------- main v2: hsE loaded from precomputed hG ----------------
__global__ __launch_bounds__(512, 4) void main_v2(
    const int* __restrict__ segp, const ushort* __restrict__ hG,
    const ushort* __restrict__ W3hP, const ushort* __restrict__ W4P,
    const float* __restrict__ gpartG, const float* __restrict__ b4,
    unsigned* __restrict__ out_enc) {
  __shared__ __align__(16) ushort hsE[MT * 256];
  __shared__ __align__(16) ushort regB[MT * 256];
  __shared__ float gpartL[MAXL * 256];
  __shared__ int segdL[MT];
  __shared__ int s_loS, nlocS;

  const int t = threadIdx.x;
  const int w = t >> 6;
  const int l = t & 63;
  const int mbeg = blockIdx.x * MT;   // NPTS % MT == 0 -> tile always full

  ushort* y1E = regB;
  unsigned* obuf = (unsigned*)regB;

  // ---- stage hsE (linear 32KB copy) + segdL ----
  {
    const size_t tb = (size_t)blockIdx.x * (MT * 256);
    #pragma unroll
    for (int i = 0; i < 4; ++i)
      *(uint4*)&hsE[(size_t)(i * 512 + t) * 8] = *(const uint4*)&hG[tb + (size_t)(i * 512 + t) * 8];
  }
  if (t < MT) segdL[t] = segp[mbeg + t];
  __syncthreads();
  if (t == 0) {
    s_loS = segdL[0];
    nlocS = segdL[MT - 1] - segdL[0] + 1;
  }
  __syncthreads();
  const int s_lo = s_loS;
  const int nloc = nlocS;
  const bool fb = (nloc > MAXL);

  float b4v[3];
  #pragma unroll
  for (int ni = 0; ni < 3; ++ni) b4v[ni] = b4[w * 48 + ni * 16 + (l & 15)];

  f32x4 acc4[MI_N][3];
  #pragma unroll
  for (int mi = 0; mi < MI_N; ++mi)
    #pragma unroll
    for (int ni = 0; ni < 3; ++ni)
      acc4[mi][ni] = (f32x4){0.f, 0.f, 0.f, 0.f};

  #pragma unroll
  for (int hf = 0; hf < 2; ++hf) {
    if (!fb) {
      for (int u = t; u < nloc * 256; u += 512) {
        int sg = u >> 8, c = u & 255;
        gpartL[u] = gpartG[(size_t)(s_lo + sg) * 512 + hf * 256 + c];
      }
    }

    f32x4 acc3[MI_N][2];
    #pragma unroll
    for (int mi = 0; mi < MI_N; ++mi)
      #pragma unroll
      for (int ni = 0; ni < 2; ++ni)
        acc3[mi][ni] = (f32x4){0.f, 0.f, 0.f, 0.f};

    {
      short8 bcur[2][2], bnxt[2][2];
      #pragma unroll
      for (int c2 = 0; c2 < 2; ++c2)
        #pragma unroll
        for (int ni = 0; ni < 2; ++ni)
          bcur[c2][ni] = *(const short8*)&W3hP[(size_t)(((c2) * 32 + hf * 16 + w * 2 + ni) * 64 + l) * 8];
      #pragma unroll
      for (int kc = 0; kc < 4; ++kc) {
        if (kc < 3) {
          #pragma unroll
          for (int c2 = 0; c2 < 2; ++c2)
            #pragma unroll
            for (int ni = 0; ni < 2; ++ni)
              bnxt[c2][ni] = *(const short8*)&W3hP[(size_t)(((kc * 2 + 2 + c2) * 32 + hf * 16 + w * 2 + ni) * 64 + l) * 8];
        }
        #pragma unroll
        for (int c2 = 0; c2 < 2; ++c2) {
          const int ks = kc * 2 + c2;
          #pragma unroll
          for (int mi = 0; mi < MI_N; ++mi) {
            short8 a = *(const short8*)&hsE[(ks * 4 + (l >> 4)) * GS + (mi * 16 + (l & 15)) * 8];
            acc3[mi][0] = __builtin_amdgcn_mfma_f32_16x16x32_bf16(a, bcur[c2][0], acc3[mi][0], 0, 0, 0);
            acc3[mi][1] = __builtin_amdgcn_mfma_f32_16x16x32_bf16(a, bcur[c2][1], acc3[mi][1], 0, 0, 0);
          }
        }
        if (kc < 3) {
          #pragma unroll
          for (int c2 = 0; c2 < 2; ++c2)
            #pragma unroll
            for (int ni = 0; ni < 2; ++ni)
              bcur[c2][ni] = bnxt[c2][ni];
        }
      }
    }
    __syncthreads();

    #pragma unroll
    for (int mi = 0; mi < MI_N; ++mi)
      #pragma unroll
      for (int ni = 0; ni < 2; ++ni) {
        int colh = w * 32 + ni * 16 + (l & 15);
        #pragma unroll
        for (int r = 0; r < 4; ++r) {
          int row = mi * 16 + (l >> 4) * 4 + r;
          int sg = segdL[row];
          float bias = fb ? gpartG[(size_t)sg * 512 + hf * 256 + colh]
                          : gpartL[(sg - s_lo) * 256 + colh];
          float v = fmaxf(acc3[mi][ni][r] + bias, 0.f);
          y1E[(colh >> 3) * GS + row * 8 + (colh & 7)] = f2bf(v);
        }
      }
    __syncthreads();

    {
      short8 bcur[2][3], bnxt[2][3];
      #pragma unroll
      for (int c2 = 0; c2 < 2; ++c2)
        #pragma unroll
        for (int ni = 0; ni < 3; ++ni)
          bcur[c2][ni] = *(const short8*)&W4P[(size_t)(((hf * 8 + c2) * 24 + w * 3 + ni) * 64 + l) * 8];
      #pragma unroll
      for (int kc = 0; kc < 4; ++kc) {
        if (kc < 3) {
          #pragma unroll
          for (int c2 = 0; c2 < 2; ++c2)
            #pragma unroll
            for (int ni = 0; ni < 3; ++ni)
              bnxt[c2][ni] = *(const short8*)&W4P[(size_t)(((hf * 8 + kc * 2 + 2 + c2) * 24 + w * 3 + ni) * 64 + l) * 8];
        }
        #pragma unroll
        for (int c2 = 0; c2 < 2; ++c2) {
          const int ks = kc * 2 + c2;
          #pragma unroll
          for (int mi = 0; mi < MI_N; ++mi) {
            short8 a = *(const short8*)&y1E[(ks * 4 + (l >> 4)) * GS + (mi * 16 + (l & 15)) * 8];
            acc4[mi][0] = __builtin_amdgcn_mfma_f32_16x16x32_bf16(a, bcur[c2][0], acc4[mi][0], 0, 0, 0);
            acc4[mi][1] = __builtin_amdgcn_mfma_f32_16x16x32_bf16(a, bcur[c2][1], acc4[mi][1], 0, 0, 0);
            acc4[mi][2] = __builtin_amdgcn_mfma_f32_16x16x32_bf16(a, bcur[c2][2], acc4[mi][2], 0, 0, 0);
          }
        }
        if (kc < 3) {
          #pragma unroll
          for (int c2 = 0; c2 < 2; ++c2)
            #pragma unroll
            for (int ni = 0; ni < 3; ++ni)
              bcur[c2][ni] = bnxt[c2][ni];
        }
      }
    }
    __syncthreads();
  }

  // ---- epilogue: merged 4-row atomic when rows share a segment ----
  if (!fb) {
    for (int u = t; u < nloc * EE; u += 512) obuf[u] = ENCNI;
    __syncthreads();
    #pragma unroll
    for (int mi = 0; mi < MI_N; ++mi) {
      int rbase = mi * 16 + (l >> 4) * 4;
      int sg0 = segdL[rbase], sg3 = segdL[rbase + 3];
      #pragma unroll
      for (int ni = 0; ni < 3; ++ni) {
        int col = w * 48 + ni * 16 + (l & 15);
        if (sg0 == sg3) {
          float m4 = fmaxf(fmaxf(acc4[mi][ni][0], acc4[mi][ni][1]),
                           fmaxf(acc4[mi][ni][2], acc4[mi][ni][3]));
          atomicMax(&obuf[(sg0 - s_lo) * EE + col], encf(m4 + b4v[ni]));
        } else {
          #pragma unroll
          for (int r = 0; r < 4; ++r)
            atomicMax(&obuf[(segdL[rbase + r] - s_lo) * EE + col],
                      encf(acc4[mi][ni][r] + b4v[ni]));
        }
      }
    }
    __syncthreads();
    for (int u = t; u < nloc * EE; u += 512) {
      unsigned e = obuf[u];
      if (e != ENCNI)
        atomicMax(&out_enc[(size_t)(s_lo + u / EE) * EE + (u % EE)], e);
    }
  } else {
    #pragma unroll
    for (int mi = 0; mi < MI_N; ++mi)
      #pragma unroll
      for (int ni = 0; ni < 3; ++ni) {
        int col = w * 48 + ni * 16 + (l & 15);
        #pragma unroll
        for (int r = 0; r < 4; ++r) {
          int row = mi * 16 + (l >> 4) * 4 + r;
          unsigned e = encf(acc4[mi][ni][r] + b4v[ni]);
          atomicMax(&out_enc[(size_t)segdL[row] * EE + col], e);
        }
      }
  }
}

// ---------------- main (R8-validated fallback, unchanged) ----------------
__global__ __launch_bounds__(512, 4) void main_kernel(
    const float* __restrict__ x, const int* __restrict__ perm,
    const int* __restrict__ segp,
    const float* __restrict__ W12, const float* __restrict__ b12,
    const ushort* __restrict__ W3hP, const ushort* __restrict__ W4P,
    const float* __restrict__ gpartG, const float* __restrict__ b4,
    unsigned* __restrict__ out_enc) {
  __shared__ __align__(16) ushort hsE[MT * 256];
  __shared__ __align__(16) ushort regB[MT * 256];
  __shared__ float gpartL[MAXL * 256];
  __shared__ int segdL[MT];
  __shared__ int s_loS, nlocS;

  const int t = threadIdx.x;
  const int w = t >> 6;
  const int l = t & 63;
  const int mbeg = blockIdx.x * MT;
  const int nvalid = min(MT, NPTS - mbeg);

  float* xsF  = (float*)regB;
  float* W12s = xsF + 704;
  float* b12s = W12s + 2816;
  ushort* y1E = regB;
  unsigned* obuf = (unsigned*)regB;

  for (int u = t; u < MT * NFEAT; u += 512) {
    int p = u / NFEAT, f = u - p * NFEAT;
    xsF[u] = (p < nvalid) ? x[(size_t)perm[mbeg + p] * NFEAT + f] : 0.f;
  }
  for (int u = t; u < 2816; u += 512) W12s[u] = W12[u];
  if (t < 256) b12s[t] = b12[t];
  if (t < MT) segdL[t] = (t < nvalid) ? segp[mbeg + t] : 0;
  __syncthreads();
  if (t == 0) {
    s_loS = segdL[0];
    nlocS = segdL[nvalid - 1] - segdL[0] + 1;
  }
  __syncthreads();
  const int s_lo = s_loS;
  const int nloc = nlocS;
  const bool fb = (nloc > MAXL);
  if (t < MT && t >= nvalid) segdL[t] = s_lo;

  #pragma unroll
  for (int i = 0; i < 4; ++i) {
    int gran = i * 8 + w;
    int cb = gran * 8;
    int row = l;
    uint4 pkt = {0, 0, 0, 0};
    if (row < nvalid) {
      float acc[8];
      #pragma unroll
      for (int cj = 0; cj < 8; ++cj) acc[cj] = b12s[cb + cj];
      #pragma unroll
      for (int f = 0; f < NFEAT; ++f) {
        float xv = xsF[row * NFEAT + f];
        #pragma unroll
        for (int cj = 0; cj < 8; ++cj) acc[cj] += W12s[(cb + cj) * NFEAT + f] * xv;
      }
      pkt.x = (unsigned)f2bf(acc[0]) | ((unsigned)f2bf(acc[1]) << 16);
      pkt.y = (unsigned)f2bf(acc[2]) | ((unsigned)f2bf(acc[3]) << 16);
      pkt.z = (unsigned)f2bf(acc[4]) | ((unsigned)f2bf(acc[5]) << 16);
      pkt.w = (unsigned)f2bf(acc[6]) | ((unsigned)f2bf(acc[7]) << 16);
    }
    *(uint4*)&hsE[gran * GS + row * 8] = pkt;
  }
  __syncthreads();

  float b4v[3];
  #pragma unroll
  for (int ni = 0; ni < 3; ++ni) b4v[ni] = b4[w * 48 + ni * 16 + (l & 15)];

  f32x4 acc4[MI_N][3];
  #pragma unroll
  for (int mi = 0; mi < MI_N; ++mi)
    #pragma unroll
    for (int ni = 0; ni < 3; ++ni)
      acc4[mi][ni] = (f32x4){0.f, 0.f, 0.f, 0.f};

  #pragma unroll
  for (int hf = 0; hf < 2; ++hf) {
    if (!fb) {
      for (int u = t; u < nloc * 256; u += 512) {
        int sg = u >> 8, c = u & 255;
        gpartL[u] = gpartG[(size_t)(s_lo + sg) * 512 + hf * 256 + c];
      }
    }

    f32x4 acc3[MI_N][2];
    #pragma unroll
    for (int mi = 0; mi < MI_N; ++mi)
      #pragma unroll
      for (int ni = 0; ni < 2; ++ni)
        acc3[mi][ni] = (f32x4){0.f, 0.f, 0.f, 0.f};

    {
      short8 bcur[2][2], bnxt[2][2];
      #pragma unroll
      for (int c2 = 0; c2 < 2; ++c2)
        #pragma unroll
        for (int ni = 0; ni < 2; ++ni)
          bcur[c2][ni] = *(const short8*)&W3hP[(size_t)(((c2) * 32 + hf * 16 + w * 2 + ni) * 64 + l) * 8];
      #pragma unroll
      for (int kc = 0; kc < 4; ++kc) {
        if (kc < 3) {
          #pragma unroll
          for (int c2 = 0; c2 < 2; ++c2)
            #pragma unroll
            for (int ni = 0; ni < 2; ++ni)
              bnxt[c2][ni] = *(const short8*)&W3hP[(size_t)(((kc * 2 + 2 + c2) * 32 + hf * 16 + w * 2 + ni) * 64 + l) * 8];
        }
        #pragma unroll
        for (int c2 = 0; c2 < 2; ++c2) {
          const int ks = kc * 2 + c2;
          #pragma unroll
          for (int mi = 0; mi < MI_N; ++mi) {
            short8 a = *(const short8*)&hsE[(ks * 4 + (l >> 4)) * GS + (mi * 16 + (l & 15)) * 8];
            acc3[mi][0] = __builtin_amdgcn_mfma_f32_16x16x32_bf16(a, bcur[c2][0], acc3[mi][0], 0, 0, 0);
            acc3[mi][1] = __builtin_amdgcn_mfma_f32_16x16x32_bf16(a, bcur[c2][1], acc3[mi][1], 0, 0, 0);
          }
        }
        if (kc < 3) {
          #pragma unroll
          for (int c2 = 0; c2 < 2; ++c2)
            #pragma unroll
            for (int ni = 0; ni < 2; ++ni)
              bcur[c2][ni] = bnxt[c2][ni];
        }
      }
    }
    __syncthreads();

    #pragma unroll
    for (int mi = 0; mi < MI_N; ++mi)
      #pragma unroll
      for (int ni = 0; ni < 2; ++ni) {
        int colh = w * 32 + ni * 16 + (l & 15);
        #pragma unroll
        for (int r = 0; r < 4; ++r) {
          int row = mi * 16 + (l >> 4) * 4 + r;
          int sg = segdL[row];
          float bias = fb ? gpartG[(size_t)sg * 512 + hf * 256 + colh]
                          : gpartL[(sg - s_lo) * 256 + colh];
          float v = fmaxf(acc3[mi][ni][r] + bias, 0.f);
          y1E[(colh >> 3) * GS + row * 8 + (colh & 7)] = f2bf(v);
        }
      }
    __syncthreads();

    {
      short8 bcur[2][3], bnxt[2][3];
      #pragma unroll
      for (int c2 = 0; c2 < 2; ++c2)
        #pragma unroll
        for (int ni = 0; ni < 3; ++ni)
          bcur[c2][ni] = *(const short8*)&W4P[(size_t)(((hf * 8 + c2) * 24 + w * 3 + ni) * 64 + l) * 8];
      #pragma unroll
      for (int kc = 0; kc < 4; ++kc) {
        if (kc < 3) {
          #pragma unroll
          for (int c2 = 0; c2 < 2; ++c2)
            #pragma unroll
            for (int ni = 0; ni < 3; ++ni)
              bnxt[c2][ni] = *(const short8*)&W4P[(size_t)(((hf * 8 + kc * 2 + 2 + c2) * 24 + w * 3 + ni) * 64 + l) * 8];
        }
        #pragma unroll
        for (int c2 = 0; c2 < 2; ++c2) {
          const int ks = kc * 2 + c2;
          #pragma unroll
          for (int mi = 0; mi < MI_N; ++mi) {
            short8 a = *(const short8*)&y1E[(ks * 4 + (l >> 4)) * GS + (mi * 16 + (l & 15)) * 8];
            acc4[mi][0] = __builtin_amdgcn_mfma_f32_16x16x32_bf16(a, bcur[c2][0], acc4[mi][0], 0, 0, 0);
            acc4[mi][1] = __builtin_amdgcn_mfma_f32_16x16x32_bf16(a, bcur[c2][1], acc4[mi][1], 0, 0, 0);
            acc4[mi][2] = __builtin_amdgcn_mfma_f32_16x16x32_bf16(a, bcur[c2][2], acc4[mi][2], 0, 0, 0);
          }
        }
        if (kc < 3) {
          #pragma unroll
          for (int c2 = 0; c2 < 2; ++c2)
            #pragma unroll
            for (int ni = 0; ni < 3; ++ni)
              bcur[c2][ni] = bnxt[c2][ni];
        }
      }
    }
    __syncthreads();
  }

  if (!fb) {
    for (int u = t; u < nloc * EE; u += 512) obuf[u] = ENCNI;
    __syncthreads();
    #pragma unroll
    for (int mi = 0; mi < MI_N; ++mi)
      #pragma unroll
      for (int ni = 0; ni < 3; ++ni) {
        int col = w * 48 + ni * 16 + (l & 15);
        #pragma unroll
        for (int r = 0; r < 4; ++r) {
          int row = mi * 16 + (l >> 4) * 4 + r;
          if (row < nvalid) {
            unsigned e = encf(acc4[mi][ni][r] + b4v[ni]);
            atomicMax(&obuf[(segdL[row] - s_lo) * EE + col], e);
          }
        }
      }
    __syncthreads();
    for (int u = t; u < nloc * EE; u += 512) {
      unsigned e = obuf[u];
      if (e != ENCNI)
        atomicMax(&out_enc[(size_t)(s_lo + u / EE) * EE + (u % EE)], e);
    }
  } else {
    #pragma unroll
    for (int mi = 0; mi < MI_N; ++mi)
      #pragma unroll
      for (int ni = 0; ni < 3; ++ni) {
        int col = w * 48 + ni * 16 + (l & 15);
        #pragma unroll
        for (int r = 0; r < 4; ++r) {
          int row = mi * 16 + (l >> 4) * 4 + r;
          if (row < nvalid) {
            unsigned e = encf(acc4[mi][ni][r] + b4v[ni]);
            atomicMax(&out_enc[(size_t)segdL[row] * EE + col], e);
          }
        }
      }
  }
}

extern "C" void kernel_launch(void* const* d_in, const int* in_sizes, int n_in,
                              void* d_out, int out_size, void* d_ws, size_t ws_size,
                              hipStream_t stream) {
  (void)in_sizes; (void)n_in; (void)out_size;
  const float* x    = (const float*)d_in[0];
  const int*   sidx = (const int*)d_in[1];
  const float* W1   = (const float*)d_in[2];
  const float* b1   = (const float*)d_in[3];
  const float* W2   = (const float*)d_in[4];
  const float* b2   = (const float*)d_in[5];
  const float* W3   = (const float*)d_in[6];
  const float* b3   = (const float*)d_in[7];
  const float* W4   = (const float*)d_in[8];
  const float* b4   = (const float*)d_in[9];
  float* out = (float*)d_out;

  char* ws = (char*)d_ws;
  size_t off = 0;
  auto alloc = [&](size_t bytes) {
    void* p = ws + off;
    off = (off + bytes + 255) & ~(size_t)255;
    return p;
  };
  int*      counts  = (int*)alloc(NSEG * 4);
  int*      cursor  = (int*)alloc(NSEG * 4);
  int*      offs    = (int*)alloc((NSEG + 1) * 4);
  int*      perm    = (int*)alloc((size_t)NPTS * 4);
  int*      segp    = (int*)alloc((size_t)NPTS * 4);
  float*    W12     = (float*)alloc(H2 * NFEAT * 4);
  float*    b12     = (float*)alloc(H2 * 4);
  float*    W3gT    = (float*)alloc((size_t)H2 * H3 * 4);
  ushort*   W3hP    = (ushort*)alloc((size_t)131072 * 2);
  ushort*   W4P     = (ushort*)alloc((size_t)196608 * 2);
  unsigned* gmaxEnc = (unsigned*)alloc((size_t)NSEG * H2 * 4);
  float*    gpartG  = (float*)alloc((size_t)NSEG * H3 * 4);
  unsigned* out_enc = (unsigned*)alloc((size_t)NSEG * EE * 4);
  ushort*   hG      = (ushort*)alloc((size_t)NPTS * 256 * 2);   // 204.8 MB
  const bool useH = (off <= ws_size);                           // deterministic

  init_all<<<(NSEG * EE + 255) / 256, 256, 0, stream>>>(counts, cursor, gmaxEnc, out_enc);
  const int preptotal = 150528 + 24576;
  prep_weights<<<(preptotal + 255) / 256, 256, 0, stream>>>(W1, b1, W2, b2, W3, W4,
                                                            W12, b12, W3gT, W3hP, W4P);
  hist_kernel<<<(NPTS + 255) / 256, 256, 0, stream>>>(sidx, counts);
  scan_kernel<<<1, 1024, 0, stream>>>(counts, offs);
  scatter_kernel<<<(NPTS + 255) / 256, 256, 0, stream>>>(sidx, offs, cursor, perm, segp);
  if (useH) {
    gmax_kernel<true><<<(NPTS + RSEG - 1) / RSEG, 512, 0, stream>>>(x, perm, segp, W12, b12, gmaxEnc, hG);
    gpart_kernel<<<NSEG / 8, 256, 0, stream>>>(gmaxEnc, W3gT, b3, gpartG);
    main_v2<<<NPTS / MT, 512, 0, stream>>>(segp, hG, W3hP, W4P, gpartG, b4, out_enc);
  } else {
    gmax_kernel<false><<<(NPTS + RSEG - 1) / RSEG, 512, 0, stream>>>(x, perm, segp, W12, b12, gmaxEnc, hG);
    gpart_kernel<<<NSEG / 8, 256, 0, stream>>>(gmaxEnc, W3gT, b3, gpartG);
    main_kernel<<<NPTS / MT, 512, 0, stream>>>(x, perm, segp, W12, b12,
                                               W3hP, W4P, gpartG, b4, out_enc);
  }
  finalize_kernel<<<(NSEG * EE + 255) / 256, 256, 0, stream>>>(out_enc, out);
}